// Round 10
// baseline (619.930 us; speedup 1.0000x reference)
//
#include <hip/hip_runtime.h>

// PerceiverAttention fused pipeline, bf16 MFMA path.
// b=8 n=4096 m=64 dim=1024 H=16 DH=64 inner=1024
// R12: (a) gemm_kv8 K-half epilogue: Kl LDS overlay first (single f2bf), then
//      coalesced vec8 K store from Kl (was 128 scalar global stores/thread).
//      (b) attn_pv rebuilt barrier-free: K/V fragments load DIRECT from global
//      (L3-resident), LDS = qs + per-wave P only (41 KB -> 3 blocks/CU),
//      per-jcol QK^T+softmax to cap VGPR, grid 1024 (8x512-key chunks),
//      O partials straight to global (32/bh), attn_fin sums 32.

using u16 = unsigned short;
typedef short bf16x8_t __attribute__((ext_vector_type(8)));
typedef float f32x4_t __attribute__((ext_vector_type(4)));

__device__ __forceinline__ u16 f2bf(float f) {
    union { float f; unsigned u; } v; v.f = f;
    unsigned r = v.u + 0x7fffu + ((v.u >> 16) & 1u);   // RNE
    return (u16)(r >> 16);
}

template <typename T> __device__ __forceinline__ T cvt_out(float v);
template <> __device__ __forceinline__ float cvt_out<float>(float v) { return v; }
template <> __device__ __forceinline__ u16   cvt_out<u16>(float v)   { return f2bf(v); }

// async global->LDS, 16B per lane; lds dest is wave-uniform base + lane*16
__device__ __forceinline__ void cp16(const void* g, void* l) {
    __builtin_amdgcn_global_load_lds((const __attribute__((address_space(1))) unsigned int*)g,
                                     (__attribute__((address_space(3))) unsigned int*)l, 16, 0, 0);
}

// ---------------- fp32 -> bf16 converts, all inputs in one launch ----------------
__global__ void cvt_all(const float* __restrict__ x, const float* __restrict__ lat,
                        const float* __restrict__ wq, const float* __restrict__ wkv,
                        const float* __restrict__ wout,
                        u16* __restrict__ xb, u16* __restrict__ latb,
                        u16* __restrict__ wqb, u16* __restrict__ wkvb,
                        u16* __restrict__ woutb) {
    int i = blockIdx.x * 256 + threadIdx.x;
    const float* s; u16* d; int off; float sc = 1.f;
    if (i < 8388608)      { s = x;    d = xb;    off = i; }
    else if (i < 8519680) { s = lat;  d = latb;  off = i - 8388608; }
    else if (i < 8781824) { s = wq;   d = wqb;   off = i - 8519680; sc = 0.125f; }
    else if (i < 9306112) { s = wkv;  d = wkvb;  off = i - 8781824; }
    else if (i < 9568256) { s = wout; d = woutb; off = i - 9306112; }
    else return;
    float4 v = ((const float4*)s)[off];
    ushort4 o;
    o.x = f2bf(v.x * sc); o.y = f2bf(v.y * sc);
    o.z = f2bf(v.z * sc); o.w = f2bf(v.w * sc);
    ((ushort4*)d)[off] = o;
}

// ---------------- merged KV GEMM, 256^2 8-phase ----------------
// A = x_bf (32768,1024); B = wkv_bf (2048,1024). Grid 1024 x 512 thr.
// bx<4: K-half -> Kl overlay -> coalesced kbuf store + fused row-max -> Mg
// bx>=4: V-half -> Vt[((b*16+h)*64+d)*4096 + j] via 2-phase LDS transpose

// stage one 128x64 half-tile (2 x cp16 rounds of 64 rows); L includes half offset
__device__ __forceinline__ void stage_half(const u16* __restrict__ G, u16* L,
                                           int grow0, int kt, int tid) {
    const int row8 = tid >> 3;            // 0..63
    const int pcb = tid & 7;
    const int sc = (pcb ^ (row8 & 7)) * 8;  // pre-swizzled source col (read applies same XOR)
    const int k0 = kt * 64;
    const int wu = (tid >> 6) * 512;      // wave-uniform u16 offset within a round
#pragma unroll
    for (int r = 0; r < 2; ++r)
        cp16(G + (size_t)(grow0 + r * 64 + row8) * 1024 + k0 + sc, L + r * 4096 + wu);
}

// one K-tile = 4 phases; stages: ph1/2 -> A-halves, ph3/4 -> B-halves
// WAIT: vmcnt immediate applied at ph4 (-1 = none)
template <bool E12, bool E34, int WAIT>
__device__ __forceinline__ void tile_phases(
    const u16* At, const u16* Bt,
    const u16* __restrict__ gA, u16* lA, int rowA, int ktA,
    const u16* __restrict__ gB, u16* lB, int rowB, int ktB,
    int wm, int wn, int frow, int pc0, int pc1, int tid,
    f32x4_t (&acc)[8][4]) {
    bf16x8_t aF[4][2], bF[4][2];
    // -------- phase 1: read A i0-3 (both ks) + B ks0; stage A-half0 --------
#pragma unroll
    for (int i = 0; i < 4; ++i) {
        const u16* p = At + (wm * 128 + i * 16 + frow) * 64;
        aF[i][0] = *(const bf16x8_t*)(p + pc0);
        aF[i][1] = *(const bf16x8_t*)(p + pc1);
    }
#pragma unroll
    for (int j = 0; j < 4; ++j)
        bF[j][0] = *(const bf16x8_t*)(Bt + (wn * 64 + j * 16 + frow) * 64 + pc0);
    if (E12) stage_half(gA, lA, rowA, ktA, tid);
    __builtin_amdgcn_s_barrier();
    asm volatile("s_waitcnt lgkmcnt(0)" ::: "memory");
    __builtin_amdgcn_s_setprio(1);
#pragma unroll
    for (int i = 0; i < 4; ++i)
#pragma unroll
        for (int j = 0; j < 4; ++j)
            acc[i][j] = __builtin_amdgcn_mfma_f32_16x16x32_bf16(aF[i][0], bF[j][0], acc[i][j], 0, 0, 0);
    __builtin_amdgcn_s_setprio(0);
    __builtin_amdgcn_s_barrier();
    // -------- phase 2: read B ks1; stage A-half1 --------
#pragma unroll
    for (int j = 0; j < 4; ++j)
        bF[j][1] = *(const bf16x8_t*)(Bt + (wn * 64 + j * 16 + frow) * 64 + pc1);
    if (E12) stage_half(gA, lA + 8192, rowA + 128, ktA, tid);
    __builtin_amdgcn_s_barrier();
    asm volatile("s_waitcnt lgkmcnt(0)" ::: "memory");
    __builtin_amdgcn_s_setprio(1);
#pragma unroll
    for (int i = 0; i < 4; ++i)
#pragma unroll
        for (int j = 0; j < 4; ++j)
            acc[i][j] = __builtin_amdgcn_mfma_f32_16x16x32_bf16(aF[i][1], bF[j][1], acc[i][j], 0, 0, 0);
    __builtin_amdgcn_s_setprio(0);
    __builtin_amdgcn_s_barrier();
    // -------- phase 3: read A i4-7 (both ks); stage B-half0 --------
#pragma unroll
    for (int i = 0; i < 4; ++i) {
        const u16* p = At + (wm * 128 + (i + 4) * 16 + frow) * 64;
        aF[i][0] = *(const bf16x8_t*)(p + pc0);
        aF[i][1] = *(const bf16x8_t*)(p + pc1);
    }
    if (E34) stage_half(gB, lB, rowB, ktB, tid);
    __builtin_amdgcn_s_barrier();
    asm volatile("s_waitcnt lgkmcnt(0)" ::: "memory");
    __builtin_amdgcn_s_setprio(1);
#pragma unroll
    for (int i = 0; i < 4; ++i)
#pragma unroll
        for (int j = 0; j < 4; ++j)
            acc[i + 4][j] = __builtin_amdgcn_mfma_f32_16x16x32_bf16(aF[i][0], bF[j][0], acc[i + 4][j], 0, 0, 0);
    __builtin_amdgcn_s_setprio(0);
    __builtin_amdgcn_s_barrier();
    // -------- phase 4: stage B-half1; counted vmcnt --------
    if (E34) stage_half(gB, lB + 8192, rowB + 128, ktB, tid);
    if (WAIT == 4)      asm volatile("s_waitcnt vmcnt(4)" ::: "memory");
    else if (WAIT == 0) asm volatile("s_waitcnt vmcnt(0)" ::: "memory");
    __builtin_amdgcn_s_barrier();
    __builtin_amdgcn_s_setprio(1);
#pragma unroll
    for (int i = 0; i < 4; ++i)
#pragma unroll
        for (int j = 0; j < 4; ++j)
            acc[i + 4][j] = __builtin_amdgcn_mfma_f32_16x16x32_bf16(aF[i][1], bF[j][1], acc[i + 4][j], 0, 0, 0);
    __builtin_amdgcn_s_setprio(0);
    __builtin_amdgcn_s_barrier();
}

__global__ __launch_bounds__(512, 2) void gemm_kv8(const u16* __restrict__ A,
                                                   const u16* __restrict__ B,
                                                   const u16* __restrict__ Qb,
                                                   const int* __restrict__ mask,
                                                   u16* __restrict__ Kc,
                                                   u16* __restrict__ Vt,
                                                   float* __restrict__ Mg2) {
    __shared__ __align__(16) u16 smem[65536];            // 128 KB: A0|A1|B0|B1
    u16* A0 = smem;
    u16* A1 = smem + 16384;
    u16* B0 = smem + 32768;
    u16* B1 = smem + 49152;
    const int tid = threadIdx.x;
    const int wid = tid >> 6, lane = tid & 63;
    const int wm = wid >> 2, wn = wid & 3;               // 2M x 4N waves, 128x64 each
    const int frow = lane & 15, fq = lane >> 4;
    const int pc0 = (fq ^ (frow & 7)) * 8;               // ks0 swizzled col offset
    const int pc1 = ((4 + fq) ^ (frow & 7)) * 8;         // ks1
    // XCD-contiguous mapping: per-XCD 16 consecutive by strips x all 8 bx
    const int fid = blockIdx.x;
    const int xcd = fid & 7, l = fid >> 3;
    const int by = xcd * 16 + (l >> 3), bx = l & 7;
    const int bm = by * 256, bn = bx * 256;

    f32x4_t acc[8][4];
#pragma unroll
    for (int i = 0; i < 8; ++i)
#pragma unroll
        for (int j = 0; j < 4; ++j) acc[i][j] = (f32x4_t){0.f, 0.f, 0.f, 0.f};

    // prologue: B0(t0), A0(t0), B1(t1) = 12 cp16; wait first 8 (tile0)
    stage_half(B, B0, bn, 0, tid);        stage_half(B, B0 + 8192, bn + 128, 0, tid);
    stage_half(A, A0, bm, 0, tid);        stage_half(A, A0 + 8192, bm + 128, 0, tid);
    stage_half(B, B1, bn, 1, tid);        stage_half(B, B1 + 8192, bn + 128, 1, tid);
    asm volatile("s_waitcnt vmcnt(4)" ::: "memory");
    __builtin_amdgcn_s_barrier();

    for (int t = 0; t < 7; ++t) {
        tile_phases<true, true, 4>(A0, B0, A, A1, bm, 2 * t + 1, B, B0, bn, 2 * t + 2,
                                   wm, wn, frow, pc0, pc1, tid, acc);
        tile_phases<true, true, 4>(A1, B1, A, A0, bm, 2 * t + 2, B, B1, bn, 2 * t + 3,
                                   wm, wn, frow, pc0, pc1, tid, acc);
    }
    tile_phases<true, false, 0>(A0, B0, A, A1, bm, 15, B, B1, bn, 0,
                                wm, wn, frow, pc0, pc1, tid, acc);
    tile_phases<false, false, -1>(A1, B1, A, A0, bm, 0, B, B1, bn, 0,
                                  wm, wn, frow, pc0, pc1, tid, acc);

    if (bx < 4) {
        // ---- K-half: Kl overlay first (single f2bf), coalesced K store, row-max ----
        const int bb = bm >> 12, jb = bm & 4095, chunk = by & 15;
        // 1) K tile -> LDS overlay [256 j][256 c], col-blocks XOR-swizzled by (j&7)
        u16* Kl = smem;                                  // 128 KB, exactly fills smem
#pragma unroll
        for (int i = 0; i < 8; ++i)
#pragma unroll
            for (int j = 0; j < 4; ++j) {
                const int cc0 = wn * 64 + j * 16 + frow;
#pragma unroll
                for (int r = 0; r < 4; ++r) {
                    const int jr = wm * 128 + i * 16 + fq * 4 + r;
                    Kl[jr * 256 + (((cc0 >> 3) ^ (jr & 7)) * 8) + (cc0 & 7)] = f2bf(acc[i][j][r]);
                }
            }
        __syncthreads();
        // 2) coalesced vec8 global K store from Kl (16 per thread, was 128 scalar)
#pragma unroll
        for (int p = 0; p < 16; ++p) {
            const int idx = p * 512 + tid;               // 0..8191
            const int jr = idx >> 5, cb = idx & 31;
            bf16x8_t v = *(const bf16x8_t*)(Kl + jr * 256 + ((cb ^ (jr & 7)) * 8));
            *(bf16x8_t*)(Kc + (size_t)(bm + jr) * 1024 + bn + cb * 8) = v;
        }
        // 3) per-wave score tile: head hh = wid>>1 (4 heads in this bx), j-half jn
        const int hh = wid >> 1, jn = (wid & 1) * 128;
        const int hc = (bx << 2) + hh;                   // global head 0..15
        int mk[8];
#pragma unroll
        for (int jf = 0; jf < 8; ++jf)
            mk[jf] = mask[bb * 4096 + jb + jn + jf * 16 + frow];
        f32x4_t s2[4][8];
#pragma unroll
        for (int i = 0; i < 4; ++i)
#pragma unroll
            for (int jf = 0; jf < 8; ++jf) s2[i][jf] = (f32x4_t){0.f, 0.f, 0.f, 0.f};
#pragma unroll
        for (int ks = 0; ks < 2; ++ks) {
            bf16x8_t aq[4], bk[8];
#pragma unroll
            for (int i = 0; i < 4; ++i)
                aq[i] = *(const bf16x8_t*)(Qb + (size_t)(bb * 64 + i * 16 + frow) * 1024 +
                                           hc * 64 + ks * 32 + fq * 8);
#pragma unroll
            for (int jf = 0; jf < 8; ++jf) {
                const int jr = jn + jf * 16 + frow;
                bk[jf] = *(const bf16x8_t*)(Kl + jr * 256 +
                                            (((hh * 8 + ks * 4 + fq) ^ (jr & 7)) * 8));
            }
#pragma unroll
            for (int i = 0; i < 4; ++i)
#pragma unroll
                for (int jf = 0; jf < 8; ++jf)
                    s2[i][jf] = __builtin_amdgcn_mfma_f32_16x16x32_bf16(aq[i], bk[jf], s2[i][jf], 0, 0, 0);
        }
        // 4) masked max over this wave's 128 keys, reduce over frow lanes
        float ml[16];
#pragma unroll
        for (int i = 0; i < 16; ++i) ml[i] = -3.0e38f;
#pragma unroll
        for (int jf = 0; jf < 8; ++jf)
            if (!mk[jf])
#pragma unroll
                for (int i = 0; i < 4; ++i)
#pragma unroll
                    for (int r = 0; r < 4; ++r)
                        ml[i * 4 + r] = fmaxf(ml[i * 4 + r], s2[i][jf][r]);
#pragma unroll
        for (int i = 0; i < 16; ++i) {
            float v = ml[i];
            v = fmaxf(v, __shfl_xor(v, 1)); v = fmaxf(v, __shfl_xor(v, 2));
            v = fmaxf(v, __shfl_xor(v, 4)); v = fmaxf(v, __shfl_xor(v, 8));
            ml[i] = v;
        }
        __syncthreads();                                 // all Kl reads complete
        float* Mp = (float*)smem;                        // [8 waves][64] overlay
        if ((lane & 15) == 0)
#pragma unroll
            for (int i = 0; i < 4; ++i)
#pragma unroll
                for (int r = 0; r < 4; ++r)
                    Mp[wid * 64 + i * 16 + fq * 4 + r] = ml[i * 4 + r];
        __syncthreads();
        if (tid < 256) {
            const int h2 = tid >> 6, m = tid & 63;
            Mg2[((size_t)(bb * 16 + (bx << 2) + h2) * 16 + chunk) * 64 + m] =
                fmaxf(Mp[(2 * h2) * 64 + m], Mp[(2 * h2 + 1) * 64 + m]);
        }
        return;
    }

    // V-half: transpose epilogue, 2 phases of 128 vd-rows through LDS overlay
    const int vb0 = bn - 1024;
    const int b = bm >> 12, jb = bm & 4095;
    u16* Ct = smem;                                      // 128 x 264 u16 = 67.6 KB
#pragma unroll
    for (int ph = 0; ph < 2; ++ph) {
        __syncthreads();
        if ((wn >> 1) == ph) {                           // waves holding these vd cols
#pragma unroll
            for (int i = 0; i < 8; ++i)
#pragma unroll
                for (int j = 0; j < 4; ++j) {
                    const int vdl = (wn & 1) * 64 + j * 16 + frow;   // 0..127
                    const int jl = wm * 128 + i * 16 + fq * 4;       // 0..255
                    ushort4 pk;
                    pk.x = f2bf(acc[i][j][0]); pk.y = f2bf(acc[i][j][1]);
                    pk.z = f2bf(acc[i][j][2]); pk.w = f2bf(acc[i][j][3]);
                    *(ushort4*)(Ct + vdl * 264 + jl) = pk;
                }
        }
        __syncthreads();
#pragma unroll
        for (int p = 0; p < 8; ++p) {
            const int idx = p * 512 + tid;               // 0..4095
            const int vdl = idx >> 5;
            const int jl = (idx & 31) * 8;
            bf16x8_t v = *(const bf16x8_t*)(Ct + vdl * 264 + jl);
            const int vd = vb0 + ph * 128 + vdl;
            const size_t addr = ((size_t)(b * 16 + (vd >> 6)) * 64 + (vd & 63)) * 4096 + jb + jl;
            *(bf16x8_t*)(Vt + addr) = v;
        }
    }
}

// ---------------- small GEMM: 64x64 tile ----------------
template <typename OutT>
__global__ __launch_bounds__(256) void gemm_bt64(const u16* __restrict__ A,
                                                 const u16* __restrict__ B,
                                                 OutT* __restrict__ C,
                                                 int M, int N, int K) {
    __shared__ __align__(16) u16 As[64 * 64];
    __shared__ __align__(16) u16 Bs[64 * 64];
    const int tid = threadIdx.x;
    const int wid = tid >> 6, lane = tid & 63;
    const int bm = blockIdx.y * 64, bn = blockIdx.x * 64;
    const int srow = lane >> 3;
    const int scol = ((lane & 7) ^ srow) * 8;
    const int frow = lane & 15;
    const int wr = (wid >> 1) * 32, wc = (wid & 1) * 32;

    f32x4_t acc[2][2];
#pragma unroll
    for (int i = 0; i < 2; ++i)
#pragma unroll
        for (int j = 0; j < 2; ++j) acc[i][j] = (f32x4_t){0.f, 0.f, 0.f, 0.f};

    for (int k0 = 0; k0 < K; k0 += 64) {
#pragma unroll
        for (int t = 0; t < 2; ++t) {
            const int c = wid * 2 + t;
            const int r = c * 8 + srow;
            cp16(A + (size_t)(bm + r) * K + k0 + scol, As + c * 512);
            cp16(B + (size_t)(bn + r) * K + k0 + scol, Bs + c * 512);
        }
        __syncthreads();
#pragma unroll
        for (int ks = 0; ks < 2; ++ks) {
            const int grp = (((ks * 4 + (lane >> 4)) ^ (frow & 7)) * 8);
            bf16x8_t af[2], bfv[2];
#pragma unroll
            for (int i = 0; i < 2; ++i) {
                af[i]  = *(const bf16x8_t*)(As + (wr + i * 16 + frow) * 64 + grp);
                bfv[i] = *(const bf16x8_t*)(Bs + (wc + i * 16 + frow) * 64 + grp);
            }
#pragma unroll
            for (int i = 0; i < 2; ++i)
#pragma unroll
                for (int j = 0; j < 2; ++j)
                    acc[i][j] = __builtin_amdgcn_mfma_f32_16x16x32_bf16(af[i], bfv[j], acc[i][j], 0, 0, 0);
        }
        __syncthreads();
    }
    const int cr = (lane >> 4) * 4, cc = lane & 15;
#pragma unroll
    for (int i = 0; i < 2; ++i)
#pragma unroll
        for (int j = 0; j < 2; ++j) {
            size_t base = (size_t)(bm + wr + i * 16 + cr) * N + (bn + wc + j * 16 + cc);
#pragma unroll
            for (int r = 0; r < 4; ++r)
                C[base + (size_t)r * N] = cvt_out<OutT>(acc[i][j][r]);
        }
}

// ---------------- attention pass 2: barrier-free, direct-global K/V ----------------
// grid 1024 = (bh, chunk of 512 keys); LDS = qs + per-wave P only (3 blocks/CU)
__global__ __launch_bounds__(256, 3) void attn_pv(const u16* __restrict__ q,
                                                  const u16* __restrict__ kbuf,
                                                  const u16* __restrict__ vtbuf,
                                                  const int* __restrict__ mask,
                                                  const float* __restrict__ Mg,
                                                  float* __restrict__ Opart,
                                                  float* __restrict__ Rpart,
                                                  float* __restrict__ loss) {
    const int c = blockIdx.x & 7, bh = blockIdx.x >> 3, b = bh >> 4, h = bh & 15;
    const int tid = threadIdx.x, wid = tid >> 6, lane = tid & 63;
    const int frow = lane & 15, fq = lane >> 4, cr = fq * 4;
    const int srow = lane >> 3, scol = ((lane & 7) ^ srow) * 8;

    __shared__ __align__(16) u16 qs[64 * 64];       // 8 KB
    __shared__ __align__(16) u16 Pw[4][4096];       // per-wave P tiles, 32 KB
    __shared__ float Mrow[64];
    __shared__ float RpS[4][64];
    __shared__ float lossP[4];

    const size_t kbase  = (size_t)b * 4096 * 1024 + (size_t)h * 64;
    const size_t vtbase = (size_t)bh * 64 * 4096;
    const int cb = c * 512;
    u16* Pl = &Pw[wid][0];

#pragma unroll
    for (int t = 0; t < 2; ++t) {
        int cq = wid * 2 + t;
        int r = cq * 8 + srow;
        cp16(q + (size_t)(b * 64 + r) * 1024 + h * 64 + scol, qs + cq * 512);
    }
    if (tid < 64) {
        float m = -3.0e38f;
#pragma unroll
        for (int cc = 0; cc < 16; ++cc) m = fmaxf(m, Mg[(size_t)(bh * 16 + cc) * 64 + tid]);
        Mrow[tid] = m;
    }
    __syncthreads();        // qs+Mrow visible; waves fully independent after this

    f32x4_t oacc[4][4];
#pragma unroll
    for (int i = 0; i < 4; ++i)
#pragma unroll
        for (int j = 0; j < 4; ++j) oacc[i][j] = (f32x4_t){0.f, 0.f, 0.f, 0.f};
    float rloc[16];
#pragma unroll
    for (int i = 0; i < 16; ++i) rloc[i] = 0.f;
    float lossacc = 0.f;

    for (int sc = 0; sc < 2; ++sc) {
        const int j0 = cb + (sc * 4 + wid) * 64;
        // Q fragments (reused across jcol)
        bf16x8_t af[4][2];
#pragma unroll
        for (int ks2 = 0; ks2 < 2; ++ks2) {
            const int grp = (((ks2 * 4 + fq) ^ (frow & 7)) * 8);
#pragma unroll
            for (int i = 0; i < 4; ++i)
                af[i][ks2] = *(const bf16x8_t*)(qs + (i * 16 + frow) * 64 + grp);
        }
        // per-jcol: QK^T (K direct from global) + softmax into Pw
#pragma unroll
        for (int jcol = 0; jcol < 4; ++jcol) {
            f32x4_t sj[4];
#pragma unroll
            for (int i = 0; i < 4; ++i) sj[i] = (f32x4_t){0.f, 0.f, 0.f, 0.f};
#pragma unroll
            for (int ks2 = 0; ks2 < 2; ++ks2) {
                bf16x8_t bk = *(const bf16x8_t*)(kbuf + kbase +
                    (size_t)(j0 + jcol * 16 + frow) * 1024 + ks2 * 32 + fq * 8);
#pragma unroll
                for (int i = 0; i < 4; ++i)
                    sj[i] = __builtin_amdgcn_mfma_f32_16x16x32_bf16(af[i][ks2], bk, sj[i], 0, 0, 0);
            }
            const int jl = jcol * 16 + frow;             // local key col 0..63
            const bool msk = mask[b * 4096 + j0 + jl] != 0;
            const int jh = jl >> 3, jlo = jl & 7;
            float c1 = 0.f, c2 = 0.f;
#pragma unroll
            for (int mt = 0; mt < 4; ++mt) {
#pragma unroll
                for (int r = 0; r < 4; ++r) {
                    const int row = mt * 16 + cr + r;
                    const float t = sj[mt][r] - Mrow[row];
                    const float p = msk ? 0.f : __expf(t);
                    rloc[mt * 4 + r] += p;
                    c1 += msk ? 0.f : t;
                    c2 += msk ? 0.f : t * t;
                    Pl[row * 64 + ((jh ^ (row & 7)) * 8) + jlo] = f2bf(p);
                }
            }
            c1 += __shfl_xor(c1, 16); c1 += __shfl_xor(c1, 32);
            c2 += __shfl_xor(c2, 16); c2 += __shfl_xor(c2, 32);
            if (lane < 16 && !msk) {
                const float var = (c2 - c1 * c1 * (1.f / 64.f)) * (1.f / 63.f);
                lossacc += fmaxf(1.f - sqrtf(var + 1e-4f), 0.f);
            }
        }
        // P@V over this wave's 64 keys; V fragments direct from global V^T
#pragma unroll
        for (int ks2 = 0; ks2 < 2; ++ks2) {
            const int grp = (((ks2 * 4 + fq) ^ (frow & 7)) * 8);
            bf16x8_t pa[4], vb[4];
#pragma unroll
            for (int i = 0; i < 4; ++i) {
                pa[i] = *(const bf16x8_t*)(Pl + (i * 16 + frow) * 64 + grp);
                vb[i] = *(const bf16x8_t*)(vtbuf + vtbase +
                        (size_t)(i * 16 + frow) * 4096 + j0 + ks2 * 32 + fq * 8);
            }
#pragma unroll
            for (int i = 0; i < 4; ++i)
#pragma unroll
                for (int j = 0; j < 4; ++j)
                    oacc[i][j] = __builtin_amdgcn_mfma_f32_16x16x32_bf16(pa[i], vb[j], oacc[i][j], 0, 0, 0);
        }
    }

    // ---------- per-wave O direct to global; R via small LDS combine ----------
    const size_t ob = ((size_t)((bh * 8 + c) * 4) + wid) * 4096;
#pragma unroll
    for (int i = 0; i < 4; ++i)
#pragma unroll
        for (int j = 0; j < 4; ++j)
#pragma unroll
            for (int r = 0; r < 4; ++r)
                Opart[ob + (size_t)(i * 16 + cr + r) * 64 + j * 16 + frow] = oacc[i][j][r];

#pragma unroll
    for (int i = 0; i < 16; ++i) {
        float v = rloc[i];
        v += __shfl_xor(v, 1); v += __shfl_xor(v, 2);
        v += __shfl_xor(v, 4); v += __shfl_xor(v, 8);
        rloc[i] = v;
    }
    if ((lane & 15) == 0) {
#pragma unroll
        for (int mt = 0; mt < 4; ++mt)
#pragma unroll
            for (int r = 0; r < 4; ++r)
                RpS[wid][mt * 16 + cr + r] = rloc[mt * 4 + r];
    }
    float v = lossacc;
    v += __shfl_xor(v, 1); v += __shfl_xor(v, 2); v += __shfl_xor(v, 4);
    v += __shfl_xor(v, 8); v += __shfl_xor(v, 16); v += __shfl_xor(v, 32);
    if (lane == 0) lossP[wid] = v;
    __syncthreads();
    if (tid < 64)
        Rpart[(size_t)(bh * 8 + c) * 64 + tid] =
            RpS[0][tid] + RpS[1][tid] + RpS[2][tid] + RpS[3][tid];
    if (tid == 0)
        atomicAdd(loss, (lossP[0] + lossP[1] + lossP[2] + lossP[3]) * (1.f / 524288.f));
}

// ---------------- attention pass 3: combine 32 chunk/wave partials ----------------
__global__ __launch_bounds__(256) void attn_fin(const float* __restrict__ Opart,
                                                const float* __restrict__ Rpart,
                                                u16* __restrict__ ao) {
    const int bh = blockIdx.x, b = bh >> 4, h = bh & 15;
    const int tid = threadIdx.x;
    __shared__ float Rt[64];
    if (tid < 64) {
        float r = 0.f;
#pragma unroll
        for (int cc = 0; cc < 8; ++cc) r += Rpart[(size_t)(bh * 8 + cc) * 64 + tid];
        Rt[tid] = r;
    }
    __syncthreads();
    for (int e4 = tid; e4 < 1024; e4 += 256) {           // float4 index within 4096
        float4 o = make_float4(0.f, 0.f, 0.f, 0.f);
#pragma unroll
        for (int p = 0; p < 32; ++p) {
            float4 s = ((const float4*)(Opart + ((size_t)(bh * 32 + p)) * 4096))[e4];
            o.x += s.x; o.y += s.y; o.z += s.z; o.w += s.w;
        }
        const int e = e4 * 4, row = e >> 6, d = e & 63;
        const float rinv = 1.f / Rt[row];
        ushort4 pk;
        pk.x = f2bf(o.x * rinv); pk.y = f2bf(o.y * rinv);
        pk.z = f2bf(o.z * rinv); pk.w = f2bf(o.w * rinv);
        *(ushort4*)(ao + (size_t)(b * 64 + row) * 1024 + h * 64 + d) = pk;
    }
}

// ---------------- host ----------------
extern "C" void kernel_launch(void* const* d_in, const int* in_sizes, int n_in,
                              void* d_out, int out_size, void* d_ws, size_t ws_size,
                              hipStream_t stream) {
    const float* x    = (const float*)d_in[0];
    const float* lat  = (const float*)d_in[1];
    const int*   mask = (const int*)d_in[2];
    const float* Wq   = (const float*)d_in[3];
    const float* Wkv  = (const float*)d_in[4];
    const float* Wout = (const float*)d_in[5];
    float* out = (float*)d_out;

    char* ws = (char*)d_ws;
    u16* x_bf    = (u16*)(ws);                    // 64 MB; Opart overlays after gemm_kv8
    u16* kbuf    = (u16*)(ws + 67108864);         // 64 MB: K (32768,1024)
    u16* vtbuf   = (u16*)(ws + 134217728);        // 64 MB: V^T (128 bh,64 d,4096 j)
    u16* wq_bf   = (u16*)(ws + 201326592);
    u16* wkv_bf  = (u16*)(ws + 203423744);
    u16* wout_bf = (u16*)(ws + 207618048);
    u16* lat_bf  = (u16*)(ws + 209715200);
    u16* q_bf    = (u16*)(ws + 210763776);
    u16* ao_bf   = (u16*)(ws + 211812352);
    // Mg + Rpart overlay wq_bf (dead after gemm_bt64<u16>; 0.5+0.25 MB < 2 MB)
    float* Mg    = (float*)(ws + 201326592);      // 128*16*64*4 = 512 KB
    float* Rpart = (float*)(ws + 201326592 + 524288);  // 128*8*64*4 = 256 KB
    // Opart overlays x_bf (dead after gemm_kv8): 128*32*4096*4 = 64 MB exactly
    float* Opart = (float*)(ws);

    hipMemsetAsync(out + 524288, 0, 4, stream);   // zero loss accumulator

    cvt_all<<<37376, 256, 0, stream>>>(x, lat, Wq, Wkv, Wout,
                                       x_bf, lat_bf, wq_bf, wkv_bf, wout_bf);

    dim3 blk(256);
    gemm_bt64<u16><<<dim3(16, 8), blk, 0, stream>>>(lat_bf, wq_bf, q_bf, 512, 1024, 1024);
    gemm_kv8<<<dim3(1024), dim3(512), 0, stream>>>(x_bf, wkv_bf, q_bf, mask, kbuf, vtbuf, Mg);
    attn_pv<<<1024, blk, 0, stream>>>(q_bf, kbuf, vtbuf, mask, Mg, Opart, Rpart, out + 524288);
    attn_fin<<<128, blk, 0, stream>>>(Opart, Rpart, ao_bf);
    gemm_bt64<float><<<dim3(16, 8), blk, 0, stream>>>(ao_bf, wout_bf, out, 512, 1024, 1024);
}

// Round 11
// 435.418 us; speedup vs baseline: 1.4238x; 1.4238x over previous
//
#include <hip/hip_runtime.h>

// PerceiverAttention fused pipeline, bf16 MFMA path.
// b=8 n=4096 m=64 dim=1024 H=16 DH=64 inner=1024
// R13: revert attn_pv/attn_fin to R11b (staged cp16 K/V, verified 437us);
//      keep R12's gemm_kv8 coalesced K-store epilogue. R12's direct-global
//      attn_pv caused 2x read (128B-line waste) + 4x write (RFO on scalar
//      f32 stores) amplification and MfmaUtil 1.5% -> 222us. Staging via
//      global_load_lds IS the efficient-traffic path.

using u16 = unsigned short;
typedef short bf16x8_t __attribute__((ext_vector_type(8)));
typedef float f32x4_t __attribute__((ext_vector_type(4)));

__device__ __forceinline__ u16 f2bf(float f) {
    union { float f; unsigned u; } v; v.f = f;
    unsigned r = v.u + 0x7fffu + ((v.u >> 16) & 1u);   // RNE
    return (u16)(r >> 16);
}

template <typename T> __device__ __forceinline__ T cvt_out(float v);
template <> __device__ __forceinline__ float cvt_out<float>(float v) { return v; }
template <> __device__ __forceinline__ u16   cvt_out<u16>(float v)   { return f2bf(v); }

// async global->LDS, 16B per lane; lds dest is wave-uniform base + lane*16
__device__ __forceinline__ void cp16(const void* g, void* l) {
    __builtin_amdgcn_global_load_lds((const __attribute__((address_space(1))) unsigned int*)g,
                                     (__attribute__((address_space(3))) unsigned int*)l, 16, 0, 0);
}

// ---------------- fp32 -> bf16 converts, all inputs in one launch ----------------
__global__ void cvt_all(const float* __restrict__ x, const float* __restrict__ lat,
                        const float* __restrict__ wq, const float* __restrict__ wkv,
                        const float* __restrict__ wout,
                        u16* __restrict__ xb, u16* __restrict__ latb,
                        u16* __restrict__ wqb, u16* __restrict__ wkvb,
                        u16* __restrict__ woutb) {
    int i = blockIdx.x * 256 + threadIdx.x;
    const float* s; u16* d; int off; float sc = 1.f;
    if (i < 8388608)      { s = x;    d = xb;    off = i; }
    else if (i < 8519680) { s = lat;  d = latb;  off = i - 8388608; }
    else if (i < 8781824) { s = wq;   d = wqb;   off = i - 8519680; sc = 0.125f; }
    else if (i < 9306112) { s = wkv;  d = wkvb;  off = i - 8781824; }
    else if (i < 9568256) { s = wout; d = woutb; off = i - 9306112; }
    else return;
    float4 v = ((const float4*)s)[off];
    ushort4 o;
    o.x = f2bf(v.x * sc); o.y = f2bf(v.y * sc);
    o.z = f2bf(v.z * sc); o.w = f2bf(v.w * sc);
    ((ushort4*)d)[off] = o;
}

// ---------------- merged KV GEMM, 256^2 8-phase ----------------
// A = x_bf (32768,1024); B = wkv_bf (2048,1024). Grid 1024 x 512 thr.
// bx<4: K-half -> Kl overlay -> coalesced kbuf store + fused row-max -> Mg
// bx>=4: V-half -> Vt[((b*16+h)*64+d)*4096 + j] via 2-phase LDS transpose

// stage one 128x64 half-tile (2 x cp16 rounds of 64 rows); L includes half offset
__device__ __forceinline__ void stage_half(const u16* __restrict__ G, u16* L,
                                           int grow0, int kt, int tid) {
    const int row8 = tid >> 3;            // 0..63
    const int pcb = tid & 7;
    const int sc = (pcb ^ (row8 & 7)) * 8;  // pre-swizzled source col (read applies same XOR)
    const int k0 = kt * 64;
    const int wu = (tid >> 6) * 512;      // wave-uniform u16 offset within a round
#pragma unroll
    for (int r = 0; r < 2; ++r)
        cp16(G + (size_t)(grow0 + r * 64 + row8) * 1024 + k0 + sc, L + r * 4096 + wu);
}

// one K-tile = 4 phases; stages: ph1/2 -> A-halves, ph3/4 -> B-halves
// WAIT: vmcnt immediate applied at ph4 (-1 = none)
template <bool E12, bool E34, int WAIT>
__device__ __forceinline__ void tile_phases(
    const u16* At, const u16* Bt,
    const u16* __restrict__ gA, u16* lA, int rowA, int ktA,
    const u16* __restrict__ gB, u16* lB, int rowB, int ktB,
    int wm, int wn, int frow, int pc0, int pc1, int tid,
    f32x4_t (&acc)[8][4]) {
    bf16x8_t aF[4][2], bF[4][2];
    // -------- phase 1: read A i0-3 (both ks) + B ks0; stage A-half0 --------
#pragma unroll
    for (int i = 0; i < 4; ++i) {
        const u16* p = At + (wm * 128 + i * 16 + frow) * 64;
        aF[i][0] = *(const bf16x8_t*)(p + pc0);
        aF[i][1] = *(const bf16x8_t*)(p + pc1);
    }
#pragma unroll
    for (int j = 0; j < 4; ++j)
        bF[j][0] = *(const bf16x8_t*)(Bt + (wn * 64 + j * 16 + frow) * 64 + pc0);
    if (E12) stage_half(gA, lA, rowA, ktA, tid);
    __builtin_amdgcn_s_barrier();
    asm volatile("s_waitcnt lgkmcnt(0)" ::: "memory");
    __builtin_amdgcn_s_setprio(1);
#pragma unroll
    for (int i = 0; i < 4; ++i)
#pragma unroll
        for (int j = 0; j < 4; ++j)
            acc[i][j] = __builtin_amdgcn_mfma_f32_16x16x32_bf16(aF[i][0], bF[j][0], acc[i][j], 0, 0, 0);
    __builtin_amdgcn_s_setprio(0);
    __builtin_amdgcn_s_barrier();
    // -------- phase 2: read B ks1; stage A-half1 --------
#pragma unroll
    for (int j = 0; j < 4; ++j)
        bF[j][1] = *(const bf16x8_t*)(Bt + (wn * 64 + j * 16 + frow) * 64 + pc1);
    if (E12) stage_half(gA, lA + 8192, rowA + 128, ktA, tid);
    __builtin_amdgcn_s_barrier();
    asm volatile("s_waitcnt lgkmcnt(0)" ::: "memory");
    __builtin_amdgcn_s_setprio(1);
#pragma unroll
    for (int i = 0; i < 4; ++i)
#pragma unroll
        for (int j = 0; j < 4; ++j)
            acc[i][j] = __builtin_amdgcn_mfma_f32_16x16x32_bf16(aF[i][1], bF[j][1], acc[i][j], 0, 0, 0);
    __builtin_amdgcn_s_setprio(0);
    __builtin_amdgcn_s_barrier();
    // -------- phase 3: read A i4-7 (both ks); stage B-half0 --------
#pragma unroll
    for (int i = 0; i < 4; ++i) {
        const u16* p = At + (wm * 128 + (i + 4) * 16 + frow) * 64;
        aF[i][0] = *(const bf16x8_t*)(p + pc0);
        aF[i][1] = *(const bf16x8_t*)(p + pc1);
    }
    if (E34) stage_half(gB, lB, rowB, ktB, tid);
    __builtin_amdgcn_s_barrier();
    asm volatile("s_waitcnt lgkmcnt(0)" ::: "memory");
    __builtin_amdgcn_s_setprio(1);
#pragma unroll
    for (int i = 0; i < 4; ++i)
#pragma unroll
        for (int j = 0; j < 4; ++j)
            acc[i + 4][j] = __builtin_amdgcn_mfma_f32_16x16x32_bf16(aF[i][0], bF[j][0], acc[i + 4][j], 0, 0, 0);
    __builtin_amdgcn_s_setprio(0);
    __builtin_amdgcn_s_barrier();
    // -------- phase 4: stage B-half1; counted vmcnt --------
    if (E34) stage_half(gB, lB + 8192, rowB + 128, ktB, tid);
    if (WAIT == 4)      asm volatile("s_waitcnt vmcnt(4)" ::: "memory");
    else if (WAIT == 0) asm volatile("s_waitcnt vmcnt(0)" ::: "memory");
    __builtin_amdgcn_s_barrier();
    __builtin_amdgcn_s_setprio(1);
#pragma unroll
    for (int i = 0; i < 4; ++i)
#pragma unroll
        for (int j = 0; j < 4; ++j)
            acc[i + 4][j] = __builtin_amdgcn_mfma_f32_16x16x32_bf16(aF[i][1], bF[j][1], acc[i + 4][j], 0, 0, 0);
    __builtin_amdgcn_s_setprio(0);
    __builtin_amdgcn_s_barrier();
}

__global__ __launch_bounds__(512, 2) void gemm_kv8(const u16* __restrict__ A,
                                                   const u16* __restrict__ B,
                                                   const u16* __restrict__ Qb,
                                                   const int* __restrict__ mask,
                                                   u16* __restrict__ Kc,
                                                   u16* __restrict__ Vt,
                                                   float* __restrict__ Mg2) {
    __shared__ __align__(16) u16 smem[65536];            // 128 KB: A0|A1|B0|B1
    u16* A0 = smem;
    u16* A1 = smem + 16384;
    u16* B0 = smem + 32768;
    u16* B1 = smem + 49152;
    const int tid = threadIdx.x;
    const int wid = tid >> 6, lane = tid & 63;
    const int wm = wid >> 2, wn = wid & 3;               // 2M x 4N waves, 128x64 each
    const int frow = lane & 15, fq = lane >> 4;
    const int pc0 = (fq ^ (frow & 7)) * 8;               // ks0 swizzled col offset
    const int pc1 = ((4 + fq) ^ (frow & 7)) * 8;         // ks1
    // XCD-contiguous mapping: per-XCD 16 consecutive by strips x all 8 bx
    const int fid = blockIdx.x;
    const int xcd = fid & 7, l = fid >> 3;
    const int by = xcd * 16 + (l >> 3), bx = l & 7;
    const int bm = by * 256, bn = bx * 256;

    f32x4_t acc[8][4];
#pragma unroll
    for (int i = 0; i < 8; ++i)
#pragma unroll
        for (int j = 0; j < 4; ++j) acc[i][j] = (f32x4_t){0.f, 0.f, 0.f, 0.f};

    // prologue: B0(t0), A0(t0), B1(t1) = 12 cp16; wait first 8 (tile0)
    stage_half(B, B0, bn, 0, tid);        stage_half(B, B0 + 8192, bn + 128, 0, tid);
    stage_half(A, A0, bm, 0, tid);        stage_half(A, A0 + 8192, bm + 128, 0, tid);
    stage_half(B, B1, bn, 1, tid);        stage_half(B, B1 + 8192, bn + 128, 1, tid);
    asm volatile("s_waitcnt vmcnt(4)" ::: "memory");
    __builtin_amdgcn_s_barrier();

    for (int t = 0; t < 7; ++t) {
        tile_phases<true, true, 4>(A0, B0, A, A1, bm, 2 * t + 1, B, B0, bn, 2 * t + 2,
                                   wm, wn, frow, pc0, pc1, tid, acc);
        tile_phases<true, true, 4>(A1, B1, A, A0, bm, 2 * t + 2, B, B1, bn, 2 * t + 3,
                                   wm, wn, frow, pc0, pc1, tid, acc);
    }
    tile_phases<true, false, 0>(A0, B0, A, A1, bm, 15, B, B1, bn, 0,
                                wm, wn, frow, pc0, pc1, tid, acc);
    tile_phases<false, false, -1>(A1, B1, A, A0, bm, 0, B, B1, bn, 0,
                                  wm, wn, frow, pc0, pc1, tid, acc);

    if (bx < 4) {
        // ---- K-half: Kl overlay first (single f2bf), coalesced K store, row-max ----
        const int bb = bm >> 12, jb = bm & 4095, chunk = by & 15;
        // 1) K tile -> LDS overlay [256 j][256 c], col-blocks XOR-swizzled by (j&7)
        u16* Kl = smem;                                  // 128 KB, exactly fills smem
#pragma unroll
        for (int i = 0; i < 8; ++i)
#pragma unroll
            for (int j = 0; j < 4; ++j) {
                const int cc0 = wn * 64 + j * 16 + frow;
#pragma unroll
                for (int r = 0; r < 4; ++r) {
                    const int jr = wm * 128 + i * 16 + fq * 4 + r;
                    Kl[jr * 256 + (((cc0 >> 3) ^ (jr & 7)) * 8) + (cc0 & 7)] = f2bf(acc[i][j][r]);
                }
            }
        __syncthreads();
        // 2) coalesced vec8 global K store from Kl (16 per thread, was 128 scalar)
#pragma unroll
        for (int p = 0; p < 16; ++p) {
            const int idx = p * 512 + tid;               // 0..8191
            const int jr = idx >> 5, cb = idx & 31;
            bf16x8_t v = *(const bf16x8_t*)(Kl + jr * 256 + ((cb ^ (jr & 7)) * 8));
            *(bf16x8_t*)(Kc + (size_t)(bm + jr) * 1024 + bn + cb * 8) = v;
        }
        // 3) per-wave score tile: head hh = wid>>1 (4 heads in this bx), j-half jn
        const int hh = wid >> 1, jn = (wid & 1) * 128;
        const int hc = (bx << 2) + hh;                   // global head 0..15
        int mk[8];
#pragma unroll
        for (int jf = 0; jf < 8; ++jf)
            mk[jf] = mask[bb * 4096 + jb + jn + jf * 16 + frow];
        f32x4_t s2[4][8];
#pragma unroll
        for (int i = 0; i < 4; ++i)
#pragma unroll
            for (int jf = 0; jf < 8; ++jf) s2[i][jf] = (f32x4_t){0.f, 0.f, 0.f, 0.f};
#pragma unroll
        for (int ks = 0; ks < 2; ++ks) {
            bf16x8_t aq[4], bk[8];
#pragma unroll
            for (int i = 0; i < 4; ++i)
                aq[i] = *(const bf16x8_t*)(Qb + (size_t)(bb * 64 + i * 16 + frow) * 1024 +
                                           hc * 64 + ks * 32 + fq * 8);
#pragma unroll
            for (int jf = 0; jf < 8; ++jf) {
                const int jr = jn + jf * 16 + frow;
                bk[jf] = *(const bf16x8_t*)(Kl + jr * 256 +
                                            (((hh * 8 + ks * 4 + fq) ^ (jr & 7)) * 8));
            }
#pragma unroll
            for (int i = 0; i < 4; ++i)
#pragma unroll
                for (int jf = 0; jf < 8; ++jf)
                    s2[i][jf] = __builtin_amdgcn_mfma_f32_16x16x32_bf16(aq[i], bk[jf], s2[i][jf], 0, 0, 0);
        }
        // 4) masked max over this wave's 128 keys, reduce over frow lanes
        float ml[16];
#pragma unroll
        for (int i = 0; i < 16; ++i) ml[i] = -3.0e38f;
#pragma unroll
        for (int jf = 0; jf < 8; ++jf)
            if (!mk[jf])
#pragma unroll
                for (int i = 0; i < 4; ++i)
#pragma unroll
                    for (int r = 0; r < 4; ++r)
                        ml[i * 4 + r] = fmaxf(ml[i * 4 + r], s2[i][jf][r]);
#pragma unroll
        for (int i = 0; i < 16; ++i) {
            float v = ml[i];
            v = fmaxf(v, __shfl_xor(v, 1)); v = fmaxf(v, __shfl_xor(v, 2));
            v = fmaxf(v, __shfl_xor(v, 4)); v = fmaxf(v, __shfl_xor(v, 8));
            ml[i] = v;
        }
        __syncthreads();                                 // all Kl reads complete
        float* Mp = (float*)smem;                        // [8 waves][64] overlay
        if ((lane & 15) == 0)
#pragma unroll
            for (int i = 0; i < 4; ++i)
#pragma unroll
                for (int r = 0; r < 4; ++r)
                    Mp[wid * 64 + i * 16 + fq * 4 + r] = ml[i * 4 + r];
        __syncthreads();
        if (tid < 256) {
            const int h2 = tid >> 6, m = tid & 63;
            Mg2[((size_t)(bb * 16 + (bx << 2) + h2) * 16 + chunk) * 64 + m] =
                fmaxf(Mp[(2 * h2) * 64 + m], Mp[(2 * h2 + 1) * 64 + m]);
        }
        return;
    }

    // V-half: transpose epilogue, 2 phases of 128 vd-rows through LDS overlay
    const int vb0 = bn - 1024;
    const int b = bm >> 12, jb = bm & 4095;
    u16* Ct = smem;                                      // 128 x 264 u16 = 67.6 KB
#pragma unroll
    for (int ph = 0; ph < 2; ++ph) {
        __syncthreads();
        if ((wn >> 1) == ph) {                           // waves holding these vd cols
#pragma unroll
            for (int i = 0; i < 8; ++i)
#pragma unroll
                for (int j = 0; j < 4; ++j) {
                    const int vdl = (wn & 1) * 64 + j * 16 + frow;   // 0..127
                    const int jl = wm * 128 + i * 16 + fq * 4;       // 0..255
                    ushort4 pk;
                    pk.x = f2bf(acc[i][j][0]); pk.y = f2bf(acc[i][j][1]);
                    pk.z = f2bf(acc[i][j][2]); pk.w = f2bf(acc[i][j][3]);
                    *(ushort4*)(Ct + vdl * 264 + jl) = pk;
                }
        }
        __syncthreads();
#pragma unroll
        for (int p = 0; p < 8; ++p) {
            const int idx = p * 512 + tid;               // 0..4095
            const int vdl = idx >> 5;
            const int jl = (idx & 31) * 8;
            bf16x8_t v = *(const bf16x8_t*)(Ct + vdl * 264 + jl);
            const int vd = vb0 + ph * 128 + vdl;
            const size_t addr = ((size_t)(b * 16 + (vd >> 6)) * 64 + (vd & 63)) * 4096 + jb + jl;
            *(bf16x8_t*)(Vt + addr) = v;
        }
    }
}

// ---------------- small GEMM: 64x64 tile ----------------
template <typename OutT>
__global__ __launch_bounds__(256) void gemm_bt64(const u16* __restrict__ A,
                                                 const u16* __restrict__ B,
                                                 OutT* __restrict__ C,
                                                 int M, int N, int K) {
    __shared__ __align__(16) u16 As[64 * 64];
    __shared__ __align__(16) u16 Bs[64 * 64];
    const int tid = threadIdx.x;
    const int wid = tid >> 6, lane = tid & 63;
    const int bm = blockIdx.y * 64, bn = blockIdx.x * 64;
    const int srow = lane >> 3;
    const int scol = ((lane & 7) ^ srow) * 8;
    const int frow = lane & 15;
    const int wr = (wid >> 1) * 32, wc = (wid & 1) * 32;

    f32x4_t acc[2][2];
#pragma unroll
    for (int i = 0; i < 2; ++i)
#pragma unroll
        for (int j = 0; j < 2; ++j) acc[i][j] = (f32x4_t){0.f, 0.f, 0.f, 0.f};

    for (int k0 = 0; k0 < K; k0 += 64) {
#pragma unroll
        for (int t = 0; t < 2; ++t) {
            const int c = wid * 2 + t;
            const int r = c * 8 + srow;
            cp16(A + (size_t)(bm + r) * K + k0 + scol, As + c * 512);
            cp16(B + (size_t)(bn + r) * K + k0 + scol, Bs + c * 512);
        }
        __syncthreads();
#pragma unroll
        for (int ks = 0; ks < 2; ++ks) {
            const int grp = (((ks * 4 + (lane >> 4)) ^ (frow & 7)) * 8);
            bf16x8_t af[2], bfv[2];
#pragma unroll
            for (int i = 0; i < 2; ++i) {
                af[i]  = *(const bf16x8_t*)(As + (wr + i * 16 + frow) * 64 + grp);
                bfv[i] = *(const bf16x8_t*)(Bs + (wc + i * 16 + frow) * 64 + grp);
            }
#pragma unroll
            for (int i = 0; i < 2; ++i)
#pragma unroll
                for (int j = 0; j < 2; ++j)
                    acc[i][j] = __builtin_amdgcn_mfma_f32_16x16x32_bf16(af[i], bfv[j], acc[i][j], 0, 0, 0);
        }
        __syncthreads();
    }
    const int cr = (lane >> 4) * 4, cc = lane & 15;
#pragma unroll
    for (int i = 0; i < 2; ++i)
#pragma unroll
        for (int j = 0; j < 2; ++j) {
            size_t base = (size_t)(bm + wr + i * 16 + cr) * N + (bn + wc + j * 16 + cc);
#pragma unroll
            for (int r = 0; r < 4; ++r)
                C[base + (size_t)r * N] = cvt_out<OutT>(acc[i][j][r]);
        }
}

// ---------------- attention pass 2: softmax+stats+P@V, barrier-free waves ----------------
// grid 512 = (bh, chunk of 1024 keys)
__global__ __launch_bounds__(256, 2) void attn_pv(const u16* __restrict__ q,
                                                  const u16* __restrict__ kbuf,
                                                  const u16* __restrict__ vtbuf,
                                                  const int* __restrict__ mask,
                                                  const float* __restrict__ Mg,
                                                  float* __restrict__ Opart,
                                                  float* __restrict__ Rpart,
                                                  float* __restrict__ loss) {
    const int c = blockIdx.x & 3, bh = blockIdx.x >> 2, b = bh >> 4, h = bh & 15;
    const int tid = threadIdx.x, wid = tid >> 6, lane = tid & 63;
    const int frow = lane & 15, cr = (lane >> 4) * 4;
    const int srow = lane >> 3, scol = ((lane & 7) ^ srow) * 8;

    __shared__ __align__(16) u16 qs[64 * 64];
    __shared__ __align__(16) u16 wbuf[4][2][4096];  // per-wave [K|P][Vt] tiles; Os overlay
    __shared__ float Mrow[64];
    __shared__ float RpS[4][64];
    __shared__ float lossP[4];

    const size_t kbase  = (size_t)b * 4096 * 1024 + (size_t)h * 64;
    const size_t vtbase = (size_t)bh * 64 * 4096;
    const int cb = c * 1024;
    u16* Kw = &wbuf[wid][0][0];
    u16* Vw = &wbuf[wid][1][0];

#pragma unroll
    for (int t = 0; t < 2; ++t) {
        int cq = wid * 2 + t;
        int r = cq * 8 + srow;
        cp16(q + (size_t)(b * 64 + r) * 1024 + h * 64 + scol, qs + cq * 512);
    }
    if (tid < 64) {
        float m = -3.0e38f;
#pragma unroll
        for (int cc = 0; cc < 16; ++cc) m = fmaxf(m, Mg[(size_t)(bh * 16 + cc) * 64 + tid]);
        Mrow[tid] = m;
    }
    __syncthreads();        // qs+Mrow visible; no more block barriers until epilogue

    f32x4_t oacc[4][4];
#pragma unroll
    for (int i = 0; i < 4; ++i)
#pragma unroll
        for (int j = 0; j < 4; ++j) oacc[i][j] = (f32x4_t){0.f, 0.f, 0.f, 0.f};
    float rloc[16];
#pragma unroll
    for (int i = 0; i < 16; ++i) rloc[i] = 0.f;
    float lossacc = 0.f;

    for (int sc = 0; sc < 4; ++sc) {
        const int j0 = cb + (sc * 4 + wid) * 64;
        // wave-private staging: K tile + Vt tile (swizzled source columns)
#pragma unroll
        for (int t = 0; t < 8; ++t) {
            int r = t * 8 + srow;
            cp16(kbuf + kbase + (size_t)(j0 + r) * 1024 + scol, Kw + t * 512);
        }
#pragma unroll
        for (int t = 0; t < 8; ++t) {
            int d = t * 8 + srow;
            cp16(vtbuf + vtbase + (size_t)d * 4096 + j0 + scol, Vw + t * 512);
        }
        __builtin_amdgcn_s_waitcnt(0);            // wave-local drain only

        // QK^T: 64 latents x this wave's 64 keys
        f32x4_t sacc[4][4];
#pragma unroll
        for (int i = 0; i < 4; ++i)
#pragma unroll
            for (int j = 0; j < 4; ++j) sacc[i][j] = (f32x4_t){0.f, 0.f, 0.f, 0.f};
#pragma unroll
        for (int ks2 = 0; ks2 < 2; ++ks2) {
            const int grp = (((ks2 * 4 + (lane >> 4)) ^ (frow & 7)) * 8);
            bf16x8_t af[4], bfv[4];
#pragma unroll
            for (int i = 0; i < 4; ++i) {
                af[i]  = *(const bf16x8_t*)(qs + (i * 16 + frow) * 64 + grp);
                bfv[i] = *(const bf16x8_t*)(Kw + (i * 16 + frow) * 64 + grp);
            }
#pragma unroll
            for (int i = 0; i < 4; ++i)
#pragma unroll
                for (int j = 0; j < 4; ++j)
                    sacc[i][j] = __builtin_amdgcn_mfma_f32_16x16x32_bf16(af[i], bfv[j], sacc[i][j], 0, 0, 0);
        }

        // softmax + variance stats; P overwrites consumed K tile (same wave, in-order LDS)
#pragma unroll
        for (int nt = 0; nt < 4; ++nt) {
            const int jl = nt * 16 + frow;               // local key col 0..63
            const bool msk = mask[b * 4096 + j0 + jl] != 0;
            const int jh = jl >> 3, jlo = jl & 7;
            float c1 = 0.f, c2 = 0.f;
#pragma unroll
            for (int mt = 0; mt < 4; ++mt) {
#pragma unroll
                for (int r = 0; r < 4; ++r) {
                    const int row = mt * 16 + cr + r;
                    const float t = sacc[mt][nt][r] - Mrow[row];
                    const float p = msk ? 0.f : __expf(t);
                    rloc[mt * 4 + r] += p;
                    c1 += msk ? 0.f : t;
                    c2 += msk ? 0.f : t * t;
                    Kw[row * 64 + ((jh ^ (row & 7)) * 8) + jlo] = f2bf(p);
                }
            }
            c1 += __shfl_xor(c1, 16); c1 += __shfl_xor(c1, 32);
            c2 += __shfl_xor(c2, 16); c2 += __shfl_xor(c2, 32);
            if (lane < 16 && !msk) {
                const float var = (c2 - c1 * c1 * (1.f / 64.f)) * (1.f / 63.f);
                lossacc += fmaxf(1.f - sqrtf(var + 1e-4f), 0.f);
            }
        }
        // P@V over this wave's 64 keys
#pragma unroll
        for (int ks2 = 0; ks2 < 2; ++ks2) {
            const int grp = (((ks2 * 4 + (lane >> 4)) ^ (frow & 7)) * 8);
            bf16x8_t pa[4], vb[4];
#pragma unroll
            for (int i = 0; i < 4; ++i) {
                pa[i] = *(const bf16x8_t*)(Kw + (i * 16 + frow) * 64 + grp);
                vb[i] = *(const bf16x8_t*)(Vw + (i * 16 + frow) * 64 + grp);
            }
#pragma unroll
            for (int i = 0; i < 4; ++i)
#pragma unroll
                for (int j = 0; j < 4; ++j)
                    oacc[i][j] = __builtin_amdgcn_mfma_f32_16x16x32_bf16(pa[i], vb[j], oacc[i][j], 0, 0, 0);
        }
    }

    // ---------- per-wave Os regions (own dead K/V space), then combine ----------
    float* Osw = (float*)(&wbuf[0][0][0]) + wid * 4096;
#pragma unroll
    for (int i = 0; i < 4; ++i)
#pragma unroll
        for (int j = 0; j < 4; ++j)
#pragma unroll
            for (int r = 0; r < 4; ++r)
                Osw[(i * 16 + cr + r) * 64 + j * 16 + frow] = oacc[i][j][r];

#pragma unroll
    for (int i = 0; i < 16; ++i) {
        float v = rloc[i];
        v += __shfl_xor(v, 1); v += __shfl_xor(v, 2);
        v += __shfl_xor(v, 4); v += __shfl_xor(v, 8);
        rloc[i] = v;
    }
    if ((lane & 15) == 0) {
#pragma unroll
        for (int mt = 0; mt < 4; ++mt)
#pragma unroll
            for (int r = 0; r < 4; ++r)
                RpS[wid][mt * 16 + cr + r] = rloc[mt * 4 + r];
    }
    float v = lossacc;
    v += __shfl_xor(v, 1); v += __shfl_xor(v, 2); v += __shfl_xor(v, 4);
    v += __shfl_xor(v, 8); v += __shfl_xor(v, 16); v += __shfl_xor(v, 32);
    if (lane == 0) lossP[wid] = v;
    __syncthreads();

    const float4* Ob4 = (const float4*)(&wbuf[0][0][0]);
    const size_t ob = (size_t)(bh * 4 + c) * 4096;
#pragma unroll
    for (int p = 0; p < 4; ++p) {
        const int e = tid + p * 256;          // float4 index 0..1023 within a 4096-f tile
        float4 s0 = Ob4[e];
        float4 s1 = Ob4[e + 1024];
        float4 s2 = Ob4[e + 2048];
        float4 s3 = Ob4[e + 3072];
        float4 o;
        o.x = s0.x + s1.x + s2.x + s3.x;
        o.y = s0.y + s1.y + s2.y + s3.y;
        o.z = s0.z + s1.z + s2.z + s3.z;
        o.w = s0.w + s1.w + s2.w + s3.w;
        ((float4*)(Opart + ob))[e] = o;
    }
    if (tid < 64)
        Rpart[(size_t)(bh * 4 + c) * 64 + tid] =
            RpS[0][tid] + RpS[1][tid] + RpS[2][tid] + RpS[3][tid];
    if (tid == 0)
        atomicAdd(loss, (lossP[0] + lossP[1] + lossP[2] + lossP[3]) * (1.f / 524288.f));
}

// ---------------- attention pass 3: combine chunk partials ----------------
__global__ __launch_bounds__(256) void attn_fin(const float* __restrict__ Opart,
                                                const float* __restrict__ Rpart,
                                                u16* __restrict__ ao) {
    const int bh = blockIdx.x, b = bh >> 4, h = bh & 15;
    const int tid = threadIdx.x;
    __shared__ float Rt[64];
    if (tid < 64) {
        float r = 0.f;
#pragma unroll
        for (int cc = 0; cc < 4; ++cc) r += Rpart[(size_t)(bh * 4 + cc) * 64 + tid];
        Rt[tid] = r;
    }
    __syncthreads();
    for (int e = tid; e < 4096; e += 256) {
        float o = 0.f;
#pragma unroll
        for (int cc = 0; cc < 4; ++cc) o += Opart[(size_t)(bh * 4 + cc) * 4096 + e];
        const int row = e >> 6, d = e & 63;
        ao[(size_t)(b * 64 + row) * 1024 + h * 64 + d] = f2bf(o / Rt[row]);
    }
}

// ---------------- host ----------------
extern "C" void kernel_launch(void* const* d_in, const int* in_sizes, int n_in,
                              void* d_out, int out_size, void* d_ws, size_t ws_size,
                              hipStream_t stream) {
    const float* x    = (const float*)d_in[0];
    const float* lat  = (const float*)d_in[1];
    const int*   mask = (const int*)d_in[2];
    const float* Wq   = (const float*)d_in[3];
    const float* Wkv  = (const float*)d_in[4];
    const float* Wout = (const float*)d_in[5];
    float* out = (float*)d_out;

    char* ws = (char*)d_ws;
    u16* x_bf    = (u16*)(ws);                    // 64 MB (partials overlay after gemm_kv8)
    u16* kbuf    = (u16*)(ws + 67108864);         // 64 MB: K (32768,1024)
    u16* vtbuf   = (u16*)(ws + 134217728);        // 64 MB: V^T (128 bh,64 d,4096 j)
    u16* wq_bf   = (u16*)(ws + 201326592);
    u16* wkv_bf  = (u16*)(ws + 203423744);
    u16* wout_bf = (u16*)(ws + 207618048);
    u16* lat_bf  = (u16*)(ws + 209715200);
    u16* q_bf    = (u16*)(ws + 210763776);
    u16* ao_bf   = (u16*)(ws + 211812352);
    // Mg overlays wq_bf (dead after gemm_bt64<u16>, before gemm_kv8 launches;
    // NOT x_bf — gemm_kv8 reads x_bf while writing Mg).
    float* Mg    = (float*)(ws + 201326592);      // 128*16*64*4 = 512 KB
    // attention partials overlay x_bf region (dead after gemm_kv8)
    float* Opart = (float*)(ws + 1048576);        // 8 MB
    float* Rpart = (float*)(ws + 1048576 + 8388608);

    hipMemsetAsync(out + 524288, 0, 4, stream);   // zero loss accumulator

    cvt_all<<<37376, 256, 0, stream>>>(x, lat, Wq, Wkv, Wout,
                                       x_bf, lat_bf, wq_bf, wkv_bf, wout_bf);

    dim3 blk(256);
    gemm_bt64<u16><<<dim3(16, 8), blk, 0, stream>>>(lat_bf, wq_bf, q_bf, 512, 1024, 1024);
    gemm_kv8<<<dim3(1024), dim3(512), 0, stream>>>(x_bf, wkv_bf, q_bf, mask, kbuf, vtbuf, Mg);
    attn_pv<<<512, blk, 0, stream>>>(q_bf, kbuf, vtbuf, mask, Mg, Opart, Rpart, out + 524288);
    attn_fin<<<128, blk, 0, stream>>>(Opart, Rpart, ao_bf);
    gemm_bt64<float><<<dim3(16, 8), blk, 0, stream>>>(ao_bf, wout_bf, out, 512, 1024, 1024);
}

// Round 12
// 422.120 us; speedup vs baseline: 1.4686x; 1.0315x over previous
//
#include <hip/hip_runtime.h>

// PerceiverAttention fused pipeline, bf16 MFMA path.
// b=8 n=4096 m=64 dim=1024 H=16 DH=64 inner=1024
// R14: attn_pv rebuilt on the counted-vmcnt pipeline (T3/T4, proven in
//      gemm_kv8): waves split latent rows (16 each); K/V staged block-wide
//      into a 2-deep double buffer (LDS 50KB -> 3 blocks/CU); per-tile
//      {QK^T, softmax+cross-wave variance, PV} then stage(t+2)+vmcnt(4)+
//      raw s_barrier — loads never drained mid-loop. R12's un-staged variant
//      amplified traffic 2-4x; R11b's staged-serial paid full latency per
//      chunk. gemm_kv8/cvt/bt64/fin identical to the measured 435us config.

using u16 = unsigned short;
typedef short bf16x8_t __attribute__((ext_vector_type(8)));
typedef float f32x4_t __attribute__((ext_vector_type(4)));

__device__ __forceinline__ u16 f2bf(float f) {
    union { float f; unsigned u; } v; v.f = f;
    unsigned r = v.u + 0x7fffu + ((v.u >> 16) & 1u);   // RNE
    return (u16)(r >> 16);
}

template <typename T> __device__ __forceinline__ T cvt_out(float v);
template <> __device__ __forceinline__ float cvt_out<float>(float v) { return v; }
template <> __device__ __forceinline__ u16   cvt_out<u16>(float v)   { return f2bf(v); }

// async global->LDS, 16B per lane; lds dest is wave-uniform base + lane*16
__device__ __forceinline__ void cp16(const void* g, void* l) {
    __builtin_amdgcn_global_load_lds((const __attribute__((address_space(1))) unsigned int*)g,
                                     (__attribute__((address_space(3))) unsigned int*)l, 16, 0, 0);
}

// ---------------- fp32 -> bf16 converts, all inputs in one launch ----------------
__global__ void cvt_all(const float* __restrict__ x, const float* __restrict__ lat,
                        const float* __restrict__ wq, const float* __restrict__ wkv,
                        const float* __restrict__ wout,
                        u16* __restrict__ xb, u16* __restrict__ latb,
                        u16* __restrict__ wqb, u16* __restrict__ wkvb,
                        u16* __restrict__ woutb) {
    int i = blockIdx.x * 256 + threadIdx.x;
    const float* s; u16* d; int off; float sc = 1.f;
    if (i < 8388608)      { s = x;    d = xb;    off = i; }
    else if (i < 8519680) { s = lat;  d = latb;  off = i - 8388608; }
    else if (i < 8781824) { s = wq;   d = wqb;   off = i - 8519680; sc = 0.125f; }
    else if (i < 9306112) { s = wkv;  d = wkvb;  off = i - 8781824; }
    else if (i < 9568256) { s = wout; d = woutb; off = i - 9306112; }
    else return;
    float4 v = ((const float4*)s)[off];
    ushort4 o;
    o.x = f2bf(v.x * sc); o.y = f2bf(v.y * sc);
    o.z = f2bf(v.z * sc); o.w = f2bf(v.w * sc);
    ((ushort4*)d)[off] = o;
}

// ---------------- merged KV GEMM, 256^2 8-phase ----------------
// A = x_bf (32768,1024); B = wkv_bf (2048,1024). Grid 1024 x 512 thr.
// bx<4: K-half -> Kl overlay -> coalesced kbuf store + fused row-max -> Mg
// bx>=4: V-half -> Vt[((b*16+h)*64+d)*4096 + j] via 2-phase LDS transpose

// stage one 128x64 half-tile (2 x cp16 rounds of 64 rows); L includes half offset
__device__ __forceinline__ void stage_half(const u16* __restrict__ G, u16* L,
                                           int grow0, int kt, int tid) {
    const int row8 = tid >> 3;            // 0..63
    const int pcb = tid & 7;
    const int sc = (pcb ^ (row8 & 7)) * 8;  // pre-swizzled source col (read applies same XOR)
    const int k0 = kt * 64;
    const int wu = (tid >> 6) * 512;      // wave-uniform u16 offset within a round
#pragma unroll
    for (int r = 0; r < 2; ++r)
        cp16(G + (size_t)(grow0 + r * 64 + row8) * 1024 + k0 + sc, L + r * 4096 + wu);
}

// one K-tile = 4 phases; stages: ph1/2 -> A-halves, ph3/4 -> B-halves
// WAIT: vmcnt immediate applied at ph4 (-1 = none)
template <bool E12, bool E34, int WAIT>
__device__ __forceinline__ void tile_phases(
    const u16* At, const u16* Bt,
    const u16* __restrict__ gA, u16* lA, int rowA, int ktA,
    const u16* __restrict__ gB, u16* lB, int rowB, int ktB,
    int wm, int wn, int frow, int pc0, int pc1, int tid,
    f32x4_t (&acc)[8][4]) {
    bf16x8_t aF[4][2], bF[4][2];
    // -------- phase 1: read A i0-3 (both ks) + B ks0; stage A-half0 --------
#pragma unroll
    for (int i = 0; i < 4; ++i) {
        const u16* p = At + (wm * 128 + i * 16 + frow) * 64;
        aF[i][0] = *(const bf16x8_t*)(p + pc0);
        aF[i][1] = *(const bf16x8_t*)(p + pc1);
    }
#pragma unroll
    for (int j = 0; j < 4; ++j)
        bF[j][0] = *(const bf16x8_t*)(Bt + (wn * 64 + j * 16 + frow) * 64 + pc0);
    if (E12) stage_half(gA, lA, rowA, ktA, tid);
    __builtin_amdgcn_s_barrier();
    asm volatile("s_waitcnt lgkmcnt(0)" ::: "memory");
    __builtin_amdgcn_s_setprio(1);
#pragma unroll
    for (int i = 0; i < 4; ++i)
#pragma unroll
        for (int j = 0; j < 4; ++j)
            acc[i][j] = __builtin_amdgcn_mfma_f32_16x16x32_bf16(aF[i][0], bF[j][0], acc[i][j], 0, 0, 0);
    __builtin_amdgcn_s_setprio(0);
    __builtin_amdgcn_s_barrier();
    // -------- phase 2: read B ks1; stage A-half1 --------
#pragma unroll
    for (int j = 0; j < 4; ++j)
        bF[j][1] = *(const bf16x8_t*)(Bt + (wn * 64 + j * 16 + frow) * 64 + pc1);
    if (E12) stage_half(gA, lA + 8192, rowA + 128, ktA, tid);
    __builtin_amdgcn_s_barrier();
    asm volatile("s_waitcnt lgkmcnt(0)" ::: "memory");
    __builtin_amdgcn_s_setprio(1);
#pragma unroll
    for (int i = 0; i < 4; ++i)
#pragma unroll
        for (int j = 0; j < 4; ++j)
            acc[i][j] = __builtin_amdgcn_mfma_f32_16x16x32_bf16(aF[i][1], bF[j][1], acc[i][j], 0, 0, 0);
    __builtin_amdgcn_s_setprio(0);
    __builtin_amdgcn_s_barrier();
    // -------- phase 3: read A i4-7 (both ks); stage B-half0 --------
#pragma unroll
    for (int i = 0; i < 4; ++i) {
        const u16* p = At + (wm * 128 + (i + 4) * 16 + frow) * 64;
        aF[i][0] = *(const bf16x8_t*)(p + pc0);
        aF[i][1] = *(const bf16x8_t*)(p + pc1);
    }
    if (E34) stage_half(gB, lB, rowB, ktB, tid);
    __builtin_amdgcn_s_barrier();
    asm volatile("s_waitcnt lgkmcnt(0)" ::: "memory");
    __builtin_amdgcn_s_setprio(1);
#pragma unroll
    for (int i = 0; i < 4; ++i)
#pragma unroll
        for (int j = 0; j < 4; ++j)
            acc[i + 4][j] = __builtin_amdgcn_mfma_f32_16x16x32_bf16(aF[i][0], bF[j][0], acc[i + 4][j], 0, 0, 0);
    __builtin_amdgcn_s_setprio(0);
    __builtin_amdgcn_s_barrier();
    // -------- phase 4: stage B-half1; counted vmcnt --------
    if (E34) stage_half(gB, lB + 8192, rowB + 128, ktB, tid);
    if (WAIT == 4)      asm volatile("s_waitcnt vmcnt(4)" ::: "memory");
    else if (WAIT == 0) asm volatile("s_waitcnt vmcnt(0)" ::: "memory");
    __builtin_amdgcn_s_barrier();
    __builtin_amdgcn_s_setprio(1);
#pragma unroll
    for (int i = 0; i < 4; ++i)
#pragma unroll
        for (int j = 0; j < 4; ++j)
            acc[i + 4][j] = __builtin_amdgcn_mfma_f32_16x16x32_bf16(aF[i][1], bF[j][1], acc[i + 4][j], 0, 0, 0);
    __builtin_amdgcn_s_setprio(0);
    __builtin_amdgcn_s_barrier();
}

__global__ __launch_bounds__(512, 2) void gemm_kv8(const u16* __restrict__ A,
                                                   const u16* __restrict__ B,
                                                   const u16* __restrict__ Qb,
                                                   const int* __restrict__ mask,
                                                   u16* __restrict__ Kc,
                                                   u16* __restrict__ Vt,
                                                   float* __restrict__ Mg2) {
    __shared__ __align__(16) u16 smem[65536];            // 128 KB: A0|A1|B0|B1
    u16* A0 = smem;
    u16* A1 = smem + 16384;
    u16* B0 = smem + 32768;
    u16* B1 = smem + 49152;
    const int tid = threadIdx.x;
    const int wid = tid >> 6, lane = tid & 63;
    const int wm = wid >> 2, wn = wid & 3;               // 2M x 4N waves, 128x64 each
    const int frow = lane & 15, fq = lane >> 4;
    const int pc0 = (fq ^ (frow & 7)) * 8;               // ks0 swizzled col offset
    const int pc1 = ((4 + fq) ^ (frow & 7)) * 8;         // ks1
    // XCD-contiguous mapping: per-XCD 16 consecutive by strips x all 8 bx
    const int fid = blockIdx.x;
    const int xcd = fid & 7, l = fid >> 3;
    const int by = xcd * 16 + (l >> 3), bx = l & 7;
    const int bm = by * 256, bn = bx * 256;

    f32x4_t acc[8][4];
#pragma unroll
    for (int i = 0; i < 8; ++i)
#pragma unroll
        for (int j = 0; j < 4; ++j) acc[i][j] = (f32x4_t){0.f, 0.f, 0.f, 0.f};

    // prologue: B0(t0), A0(t0), B1(t1) = 12 cp16; wait first 8 (tile0)
    stage_half(B, B0, bn, 0, tid);        stage_half(B, B0 + 8192, bn + 128, 0, tid);
    stage_half(A, A0, bm, 0, tid);        stage_half(A, A0 + 8192, bm + 128, 0, tid);
    stage_half(B, B1, bn, 1, tid);        stage_half(B, B1 + 8192, bn + 128, 1, tid);
    asm volatile("s_waitcnt vmcnt(4)" ::: "memory");
    __builtin_amdgcn_s_barrier();

    for (int t = 0; t < 7; ++t) {
        tile_phases<true, true, 4>(A0, B0, A, A1, bm, 2 * t + 1, B, B0, bn, 2 * t + 2,
                                   wm, wn, frow, pc0, pc1, tid, acc);
        tile_phases<true, true, 4>(A1, B1, A, A0, bm, 2 * t + 2, B, B1, bn, 2 * t + 3,
                                   wm, wn, frow, pc0, pc1, tid, acc);
    }
    tile_phases<true, false, 0>(A0, B0, A, A1, bm, 15, B, B1, bn, 0,
                                wm, wn, frow, pc0, pc1, tid, acc);
    tile_phases<false, false, -1>(A1, B1, A, A0, bm, 0, B, B1, bn, 0,
                                  wm, wn, frow, pc0, pc1, tid, acc);

    if (bx < 4) {
        // ---- K-half: Kl overlay first (single f2bf), coalesced K store, row-max ----
        const int bb = bm >> 12, jb = bm & 4095, chunk = by & 15;
        // 1) K tile -> LDS overlay [256 j][256 c], col-blocks XOR-swizzled by (j&7)
        u16* Kl = smem;                                  // 128 KB, exactly fills smem
#pragma unroll
        for (int i = 0; i < 8; ++i)
#pragma unroll
            for (int j = 0; j < 4; ++j) {
                const int cc0 = wn * 64 + j * 16 + frow;
#pragma unroll
                for (int r = 0; r < 4; ++r) {
                    const int jr = wm * 128 + i * 16 + fq * 4 + r;
                    Kl[jr * 256 + (((cc0 >> 3) ^ (jr & 7)) * 8) + (cc0 & 7)] = f2bf(acc[i][j][r]);
                }
            }
        __syncthreads();
        // 2) coalesced vec8 global K store from Kl (16 per thread, was 128 scalar)
#pragma unroll
        for (int p = 0; p < 16; ++p) {
            const int idx = p * 512 + tid;               // 0..8191
            const int jr = idx >> 5, cb = idx & 31;
            bf16x8_t v = *(const bf16x8_t*)(Kl + jr * 256 + ((cb ^ (jr & 7)) * 8));
            *(bf16x8_t*)(Kc + (size_t)(bm + jr) * 1024 + bn + cb * 8) = v;
        }
        // 3) per-wave score tile: head hh = wid>>1 (4 heads in this bx), j-half jn
        const int hh = wid >> 1, jn = (wid & 1) * 128;
        const int hc = (bx << 2) + hh;                   // global head 0..15
        int mk[8];
#pragma unroll
        for (int jf = 0; jf < 8; ++jf)
            mk[jf] = mask[bb * 4096 + jb + jn + jf * 16 + frow];
        f32x4_t s2[4][8];
#pragma unroll
        for (int i = 0; i < 4; ++i)
#pragma unroll
            for (int jf = 0; jf < 8; ++jf) s2[i][jf] = (f32x4_t){0.f, 0.f, 0.f, 0.f};
#pragma unroll
        for (int ks = 0; ks < 2; ++ks) {
            bf16x8_t aq[4], bk[8];
#pragma unroll
            for (int i = 0; i < 4; ++i)
                aq[i] = *(const bf16x8_t*)(Qb + (size_t)(bb * 64 + i * 16 + frow) * 1024 +
                                           hc * 64 + ks * 32 + fq * 8);
#pragma unroll
            for (int jf = 0; jf < 8; ++jf) {
                const int jr = jn + jf * 16 + frow;
                bk[jf] = *(const bf16x8_t*)(Kl + jr * 256 +
                                            (((hh * 8 + ks * 4 + fq) ^ (jr & 7)) * 8));
            }
#pragma unroll
            for (int i = 0; i < 4; ++i)
#pragma unroll
                for (int jf = 0; jf < 8; ++jf)
                    s2[i][jf] = __builtin_amdgcn_mfma_f32_16x16x32_bf16(aq[i], bk[jf], s2[i][jf], 0, 0, 0);
        }
        // 4) masked max over this wave's 128 keys, reduce over frow lanes
        float ml[16];
#pragma unroll
        for (int i = 0; i < 16; ++i) ml[i] = -3.0e38f;
#pragma unroll
        for (int jf = 0; jf < 8; ++jf)
            if (!mk[jf])
#pragma unroll
                for (int i = 0; i < 4; ++i)
#pragma unroll
                    for (int r = 0; r < 4; ++r)
                        ml[i * 4 + r] = fmaxf(ml[i * 4 + r], s2[i][jf][r]);
#pragma unroll
        for (int i = 0; i < 16; ++i) {
            float v = ml[i];
            v = fmaxf(v, __shfl_xor(v, 1)); v = fmaxf(v, __shfl_xor(v, 2));
            v = fmaxf(v, __shfl_xor(v, 4)); v = fmaxf(v, __shfl_xor(v, 8));
            ml[i] = v;
        }
        __syncthreads();                                 // all Kl reads complete
        float* Mp = (float*)smem;                        // [8 waves][64] overlay
        if ((lane & 15) == 0)
#pragma unroll
            for (int i = 0; i < 4; ++i)
#pragma unroll
                for (int r = 0; r < 4; ++r)
                    Mp[wid * 64 + i * 16 + fq * 4 + r] = ml[i * 4 + r];
        __syncthreads();
        if (tid < 256) {
            const int h2 = tid >> 6, m = tid & 63;
            Mg2[((size_t)(bb * 16 + (bx << 2) + h2) * 16 + chunk) * 64 + m] =
                fmaxf(Mp[(2 * h2) * 64 + m], Mp[(2 * h2 + 1) * 64 + m]);
        }
        return;
    }

    // V-half: transpose epilogue, 2 phases of 128 vd-rows through LDS overlay
    const int vb0 = bn - 1024;
    const int b = bm >> 12, jb = bm & 4095;
    u16* Ct = smem;                                      // 128 x 264 u16 = 67.6 KB
#pragma unroll
    for (int ph = 0; ph < 2; ++ph) {
        __syncthreads();
        if ((wn >> 1) == ph) {                           // waves holding these vd cols
#pragma unroll
            for (int i = 0; i < 8; ++i)
#pragma unroll
                for (int j = 0; j < 4; ++j) {
                    const int vdl = (wn & 1) * 64 + j * 16 + frow;   // 0..127
                    const int jl = wm * 128 + i * 16 + fq * 4;       // 0..255
                    ushort4 pk;
                    pk.x = f2bf(acc[i][j][0]); pk.y = f2bf(acc[i][j][1]);
                    pk.z = f2bf(acc[i][j][2]); pk.w = f2bf(acc[i][j][3]);
                    *(ushort4*)(Ct + vdl * 264 + jl) = pk;
                }
        }
        __syncthreads();
#pragma unroll
        for (int p = 0; p < 8; ++p) {
            const int idx = p * 512 + tid;               // 0..4095
            const int vdl = idx >> 5;
            const int jl = (idx & 31) * 8;
            bf16x8_t v = *(const bf16x8_t*)(Ct + vdl * 264 + jl);
            const int vd = vb0 + ph * 128 + vdl;
            const size_t addr = ((size_t)(b * 16 + (vd >> 6)) * 64 + (vd & 63)) * 4096 + jb + jl;
            *(bf16x8_t*)(Vt + addr) = v;
        }
    }
}

// ---------------- small GEMM: 64x64 tile ----------------
template <typename OutT>
__global__ __launch_bounds__(256) void gemm_bt64(const u16* __restrict__ A,
                                                 const u16* __restrict__ B,
                                                 OutT* __restrict__ C,
                                                 int M, int N, int K) {
    __shared__ __align__(16) u16 As[64 * 64];
    __shared__ __align__(16) u16 Bs[64 * 64];
    const int tid = threadIdx.x;
    const int wid = tid >> 6, lane = tid & 63;
    const int bm = blockIdx.y * 64, bn = blockIdx.x * 64;
    const int srow = lane >> 3;
    const int scol = ((lane & 7) ^ srow) * 8;
    const int frow = lane & 15;
    const int wr = (wid >> 1) * 32, wc = (wid & 1) * 32;

    f32x4_t acc[2][2];
#pragma unroll
    for (int i = 0; i < 2; ++i)
#pragma unroll
        for (int j = 0; j < 2; ++j) acc[i][j] = (f32x4_t){0.f, 0.f, 0.f, 0.f};

    for (int k0 = 0; k0 < K; k0 += 64) {
#pragma unroll
        for (int t = 0; t < 2; ++t) {
            const int c = wid * 2 + t;
            const int r = c * 8 + srow;
            cp16(A + (size_t)(bm + r) * K + k0 + scol, As + c * 512);
            cp16(B + (size_t)(bn + r) * K + k0 + scol, Bs + c * 512);
        }
        __syncthreads();
#pragma unroll
        for (int ks = 0; ks < 2; ++ks) {
            const int grp = (((ks * 4 + (lane >> 4)) ^ (frow & 7)) * 8);
            bf16x8_t af[2], bfv[2];
#pragma unroll
            for (int i = 0; i < 2; ++i) {
                af[i]  = *(const bf16x8_t*)(As + (wr + i * 16 + frow) * 64 + grp);
                bfv[i] = *(const bf16x8_t*)(Bs + (wc + i * 16 + frow) * 64 + grp);
            }
#pragma unroll
            for (int i = 0; i < 2; ++i)
#pragma unroll
                for (int j = 0; j < 2; ++j)
                    acc[i][j] = __builtin_amdgcn_mfma_f32_16x16x32_bf16(af[i], bfv[j], acc[i][j], 0, 0, 0);
        }
        __syncthreads();
    }
    const int cr = (lane >> 4) * 4, cc = lane & 15;
#pragma unroll
    for (int i = 0; i < 2; ++i)
#pragma unroll
        for (int j = 0; j < 2; ++j) {
            size_t base = (size_t)(bm + wr + i * 16 + cr) * N + (bn + wc + j * 16 + cc);
#pragma unroll
            for (int r = 0; r < 4; ++r)
                C[base + (size_t)r * N] = cvt_out<OutT>(acc[i][j][r]);
        }
}

// ---------------- attention pass 2: pipelined staged K/V, waves split latents ----------------
// grid 512 = (bh, chunk of 1024 keys); 16 kv-tiles of 64 keys, 2-deep dbuf,
// counted vmcnt(4) (T3/T4). LDS ~50KB -> 3 blocks/CU.
__global__ __launch_bounds__(256, 3) void attn_pv(const u16* __restrict__ q,
                                                  const u16* __restrict__ kbuf,
                                                  const u16* __restrict__ vtbuf,
                                                  const int* __restrict__ mask,
                                                  const float* __restrict__ Mg,
                                                  float* __restrict__ Opart,
                                                  float* __restrict__ Rpart,
                                                  float* __restrict__ loss) {
    const int c = blockIdx.x & 3, bh = blockIdx.x >> 2, b = bh >> 4, h = bh & 15;
    const int tid = threadIdx.x, wid = tid >> 6, lane = tid & 63;
    const int frow = lane & 15, fq = lane >> 4;
    const int srow = lane >> 3, scol8 = ((lane & 7) ^ srow) * 8;

    __shared__ __align__(16) u16 qs[4096];        // 8 KB: Q 64x64 (head slice)
    __shared__ __align__(16) u16 kv[4][4096];     // 32 KB: K0|K1|V0|V1 (dbuf)
    __shared__ __align__(16) u16 Pw[4][1024];     // 8 KB: per-wave P 16x64
    __shared__ float cstat[4][2][64];             // 2 KB: per-wave c1/c2 per key
    __shared__ float Mrow[64];

    const size_t kbase  = (size_t)b * 4096 * 1024 + (size_t)h * 64;
    const size_t vtbase = (size_t)bh * 64 * 4096;
    const int cb = c * 1024;
    const int s_c = tid & 7, s_r0 = tid >> 3;     // staging col-block / row base
    const int wu = wid * 512;                     // wave-uniform LDS offset (u16)

    // ---- prologue: Q, Mrow, tiles 0+1 staged; counted wait ----
#pragma unroll
    for (int t = 0; t < 2; ++t) {
        int cq = wid * 2 + t;
        int r = cq * 8 + srow;
        cp16(q + (size_t)(b * 64 + r) * 1024 + h * 64 + scol8, qs + cq * 512);
    }
    if (tid < 64) {
        float m = -3.0e38f;
#pragma unroll
        for (int cc = 0; cc < 16; ++cc) m = fmaxf(m, Mg[(size_t)(bh * 16 + cc) * 64 + tid]);
        Mrow[tid] = m;
    }
#pragma unroll
    for (int sel = 0; sel < 2; ++sel) {           // stage tiles 0 and 1
        const int j0 = cb + sel * 64;
#pragma unroll
        for (int rnd = 0; rnd < 2; ++rnd) {
            const int row = rnd * 32 + s_r0;
            const int sc = (s_c ^ (row & 7)) * 8;
            cp16(kbuf + kbase + (size_t)(j0 + row) * 1024 + sc, kv[sel] + rnd * 2048 + wu);
        }
#pragma unroll
        for (int rnd = 0; rnd < 2; ++rnd) {
            const int row = rnd * 32 + s_r0;
            const int sc = (s_c ^ (row & 7)) * 8;
            cp16(vtbuf + vtbase + (size_t)row * 4096 + j0 + sc, kv[2 + sel] + rnd * 2048 + wu);
        }
    }
    asm volatile("s_waitcnt vmcnt(4) lgkmcnt(0)" ::: "memory");  // Q+Mrow+tile0 ready
    __builtin_amdgcn_s_barrier();

    // Q fragments (constant across tiles): rows wid*16+frow
    bf16x8_t af[2];
#pragma unroll
    for (int ks = 0; ks < 2; ++ks)
        af[ks] = *(const bf16x8_t*)(qs + (wid * 16 + frow) * 64 + (((ks * 4 + fq) ^ (frow & 7)) * 8));
    float mr[4];
#pragma unroll
    for (int r = 0; r < 4; ++r) mr[r] = Mrow[wid * 16 + fq * 4 + r];

    f32x4_t oacc[4];
#pragma unroll
    for (int dj = 0; dj < 4; ++dj) oacc[dj] = (f32x4_t){0.f, 0.f, 0.f, 0.f};
    float rloc[4] = {0.f, 0.f, 0.f, 0.f};
    float lossacc = 0.f;

    for (int t = 0; t < 16; ++t) {
        const int sel = t & 1;
        const int j0 = cb + t * 64;
        const u16* Kc_ = kv[sel];
        const u16* Vc_ = kv[2 + sel];
        int mk[4];
#pragma unroll
        for (int j = 0; j < 4; ++j) mk[j] = mask[b * 4096 + j0 + j * 16 + frow];

        // QK^T: 16 latent rows x 64 keys
        f32x4_t sacc[4];
#pragma unroll
        for (int j = 0; j < 4; ++j) sacc[j] = (f32x4_t){0.f, 0.f, 0.f, 0.f};
#pragma unroll
        for (int ks = 0; ks < 2; ++ks) {
            const int kswz = ((ks * 4 + fq) ^ (frow & 7)) * 8;
#pragma unroll
            for (int j = 0; j < 4; ++j) {
                bf16x8_t bk = *(const bf16x8_t*)(Kc_ + (j * 16 + frow) * 64 + kswz);
                sacc[j] = __builtin_amdgcn_mfma_f32_16x16x32_bf16(af[ks], bk, sacc[j], 0, 0, 0);
            }
        }
        // softmax + variance partials; P -> wave-private LDS
        float c1l[4] = {0.f, 0.f, 0.f, 0.f}, c2l[4] = {0.f, 0.f, 0.f, 0.f};
#pragma unroll
        for (int j = 0; j < 4; ++j) {
#pragma unroll
            for (int r = 0; r < 4; ++r) {
                const int rowl = fq * 4 + r;
                const float tv = sacc[j][r] - mr[r];
                const float p = mk[j] ? 0.f : __expf(tv);
                rloc[r] += p;
                c1l[j] += mk[j] ? 0.f : tv;
                c2l[j] += mk[j] ? 0.f : tv * tv;
                const int jc = j * 2 + (frow >> 3);
                Pw[wid][rowl * 64 + ((jc ^ (rowl & 7)) * 8) + (frow & 7)] = f2bf(p);
            }
            c1l[j] += __shfl_xor(c1l[j], 16); c1l[j] += __shfl_xor(c1l[j], 32);
            c2l[j] += __shfl_xor(c2l[j], 16); c2l[j] += __shfl_xor(c2l[j], 32);
            if (fq == 0) {
                cstat[wid][0][j * 16 + frow] = c1l[j];
                cstat[wid][1][j * 16 + frow] = c2l[j];
            }
        }
        asm volatile("s_waitcnt lgkmcnt(0)" ::: "memory");
        __builtin_amdgcn_s_barrier();                 // B1: cstat visible
        if (wid == 0) {
            const float c1t = cstat[0][0][lane] + cstat[1][0][lane] + cstat[2][0][lane] + cstat[3][0][lane];
            const float c2t = cstat[0][1][lane] + cstat[1][1][lane] + cstat[2][1][lane] + cstat[3][1][lane];
            if (!mask[b * 4096 + j0 + lane]) {
                const float var = (c2t - c1t * c1t * (1.f / 64.f)) * (1.f / 63.f);
                lossacc += fmaxf(1.f - sqrtf(var + 1e-4f), 0.f);
            }
        }
        // PV: O[16][64] += P[16][64] x V[64 keys][64 d]
#pragma unroll
        for (int ks = 0; ks < 2; ++ks) {
            const int kswz = ((ks * 4 + fq) ^ (frow & 7)) * 8;
            bf16x8_t pa = *(const bf16x8_t*)(Pw[wid] + frow * 64 + kswz);
#pragma unroll
            for (int dj = 0; dj < 4; ++dj) {
                bf16x8_t vb = *(const bf16x8_t*)(Vc_ + (dj * 16 + frow) * 64 + kswz);
                oacc[dj] = __builtin_amdgcn_mfma_f32_16x16x32_bf16(pa, vb, oacc[dj], 0, 0, 0);
            }
        }
        asm volatile("s_waitcnt lgkmcnt(0)" ::: "memory");
        __builtin_amdgcn_s_barrier();                 // B2: kv[sel] reads done
        if (t < 14) {
            const int jn = cb + (t + 2) * 64;
#pragma unroll
            for (int rnd = 0; rnd < 2; ++rnd) {
                const int row = rnd * 32 + s_r0;
                const int sc = (s_c ^ (row & 7)) * 8;
                cp16(kbuf + kbase + (size_t)(jn + row) * 1024 + sc, kv[sel] + rnd * 2048 + wu);
            }
#pragma unroll
            for (int rnd = 0; rnd < 2; ++rnd) {
                const int row = rnd * 32 + s_r0;
                const int sc = (s_c ^ (row & 7)) * 8;
                cp16(vtbuf + vtbase + (size_t)row * 4096 + jn + sc, kv[2 + sel] + rnd * 2048 + wu);
            }
            asm volatile("s_waitcnt vmcnt(4)" ::: "memory");   // tile t+1 landed
            __builtin_amdgcn_s_barrier();             // B3
        } else if (t == 14) {
            asm volatile("s_waitcnt vmcnt(0)" ::: "memory");   // tile 15 landed
            __builtin_amdgcn_s_barrier();             // B3
        }
    }

    // ---- epilogue: O via LDS overlay (kv dead after last B2), coalesced out ----
    float* Ol = (float*)&kv[0][0];                    // 16 KB of the 32 KB kv area
#pragma unroll
    for (int dj = 0; dj < 4; ++dj)
#pragma unroll
        for (int r = 0; r < 4; ++r)
            Ol[(wid * 16 + fq * 4 + r) * 64 + dj * 16 + frow] = oacc[dj][r];

    // R: reduce rloc over frow lanes
#pragma unroll
    for (int r = 0; r < 4; ++r) {
        float v = rloc[r];
        v += __shfl_xor(v, 1); v += __shfl_xor(v, 2);
        v += __shfl_xor(v, 4); v += __shfl_xor(v, 8);
        rloc[r] = v;
    }
    if (frow == 0)
#pragma unroll
        for (int r = 0; r < 4; ++r)
            Rpart[(size_t)(bh * 4 + c) * 64 + wid * 16 + fq * 4 + r] = rloc[r];

    if (wid == 0) {                                   // loss: reduce 64 lanes
        float v = lossacc;
        v += __shfl_xor(v, 1); v += __shfl_xor(v, 2); v += __shfl_xor(v, 4);
        v += __shfl_xor(v, 8); v += __shfl_xor(v, 16); v += __shfl_xor(v, 32);
        if (lane == 0) atomicAdd(loss, v * (1.f / 524288.f));
    }

    asm volatile("s_waitcnt lgkmcnt(0)" ::: "memory");
    __builtin_amdgcn_s_barrier();
    const size_t ob = (size_t)(bh * 4 + c) * 4096;
#pragma unroll
    for (int p = 0; p < 4; ++p) {
        const int e = p * 256 + tid;                  // float4 index 0..1023
        ((float4*)(Opart + ob))[e] = ((const float4*)Ol)[e];
    }
}

// ---------------- attention pass 3: combine chunk partials ----------------
__global__ __launch_bounds__(256) void attn_fin(const float* __restrict__ Opart,
                                                const float* __restrict__ Rpart,
                                                u16* __restrict__ ao) {
    const int bh = blockIdx.x, b = bh >> 4, h = bh & 15;
    const int tid = threadIdx.x;
    __shared__ float Rt[64];
    if (tid < 64) {
        float r = 0.f;
#pragma unroll
        for (int cc = 0; cc < 4; ++cc) r += Rpart[(size_t)(bh * 4 + cc) * 64 + tid];
        Rt[tid] = r;
    }
    __syncthreads();
    for (int e = tid; e < 4096; e += 256) {
        float o = 0.f;
#pragma unroll
        for (int cc = 0; cc < 4; ++cc) o += Opart[(size_t)(bh * 4 + cc) * 4096 + e];
        const int row = e >> 6, d = e & 63;
        ao[(size_t)(b * 64 + row) * 1024 + h * 64 + d] = f2bf(o / Rt[row]);
    }
}

// ---------------- host ----------------
extern "C" void kernel_launch(void* const* d_in, const int* in_sizes, int n_in,
                              void* d_out, int out_size, void* d_ws, size_t ws_size,
                              hipStream_t stream) {
    const float* x    = (const float*)d_in[0];
    const float* lat  = (const float*)d_in[1];
    const int*   mask = (const int*)d_in[2];
    const float* Wq   = (const float*)d_in[3];
    const float* Wkv  = (const float*)d_in[4];
    const float* Wout = (const float*)d_in[5];
    float* out = (float*)d_out;

    char* ws = (char*)d_ws;
    u16* x_bf    = (u16*)(ws);                    // 64 MB (partials overlay after gemm_kv8)
    u16* kbuf    = (u16*)(ws + 67108864);         // 64 MB: K (32768,1024)
    u16* vtbuf   = (u16*)(ws + 134217728);        // 64 MB: V^T (128 bh,64 d,4096 j)
    u16* wq_bf   = (u16*)(ws + 201326592);
    u16* wkv_bf  = (u16*)(ws + 203423744);
    u16* wout_bf = (u16*)(ws + 207618048);
    u16* lat_bf  = (u16*)(ws + 209715200);
    u16* q_bf    = (u16*)(ws + 210763776);
    u16* ao_bf   = (u16*)(ws + 211812352);
    // Mg overlays wq_bf (dead after gemm_bt64<u16>, before gemm_kv8 launches;
    // NOT x_bf — gemm_kv8 reads x_bf while writing Mg).
    float* Mg    = (float*)(ws + 201326592);      // 128*16*64*4 = 512 KB
    // attention partials overlay x_bf region (dead after gemm_kv8)
    float* Opart = (float*)(ws + 1048576);        // 8 MB
    float* Rpart = (float*)(ws + 1048576 + 8388608);

    hipMemsetAsync(out + 524288, 0, 4, stream);   // zero loss accumulator

    cvt_all<<<37376, 256, 0, stream>>>(x, lat, Wq, Wkv, Wout,
                                       x_bf, lat_bf, wq_bf, wkv_bf, wout_bf);

    dim3 blk(256);
    gemm_bt64<u16><<<dim3(16, 8), blk, 0, stream>>>(lat_bf, wq_bf, q_bf, 512, 1024, 1024);
    gemm_kv8<<<dim3(1024), dim3(512), 0, stream>>>(x_bf, wkv_bf, q_bf, mask, kbuf, vtbuf, Mg);
    attn_pv<<<512, blk, 0, stream>>>(q_bf, kbuf, vtbuf, mask, Mg, Opart, Rpart, out + 524288);
    attn_fin<<<128, blk, 0, stream>>>(Opart, Rpart, ao_bf);
    gemm_bt64<float><<<dim3(16, 8), blk, 0, stream>>>(ao_bf, wout_bf, out, 512, 1024, 1024);
}